// Round 8
// baseline (293.669 us; speedup 1.0000x reference)
//
#include <hip/hip_runtime.h>
#include <hip/hip_bf16.h>
#include <stdint.h>

#define DEV __device__ __forceinline__

typedef __attribute__((ext_vector_type(8))) short short8;
typedef __attribute__((ext_vector_type(8))) __bf16 bf16x8;
typedef __attribute__((ext_vector_type(4))) float f32x4;

typedef const __attribute__((address_space(1))) uint32_t gu32;
typedef __attribute__((address_space(3))) uint32_t lu32;

DEV void gload16(const void* g, void* l) {
  __builtin_amdgcn_global_load_lds((gu32*)g, (lu32*)l, 16, 0, 0);
}

DEV f32x4 mfma16(bf16x8 a, bf16x8 b, f32x4 c) {
  return __builtin_amdgcn_mfma_f32_16x16x32_bf16(a, b, c, 0, 0, 0);
}

DEV __hip_bfloat16 f2bf(float x) { return __float2bfloat16(x); }
DEV bf16x8 as_bf(short8 v) { union { short8 s; bf16x8 b; } u; u.s = v; return u.b; }

// ---------------------------------------------------------------------------
// f32 -> bf16 elementwise convert (n multiple of 8).
// ---------------------------------------------------------------------------
__global__ __launch_bounds__(256)
void cvt_f32_bf16(const float* __restrict__ src, __hip_bfloat16* __restrict__ dst, int n)
{
  int i = (blockIdx.x * 256 + threadIdx.x) * 8;
  if (i >= n) return;
  f32x4 a = *(const f32x4*)&src[i];
  f32x4 b = *(const f32x4*)&src[i + 4];
  short8 o;
#pragma unroll
  for (int j = 0; j < 4; ++j) {
    o[j]     = __bfloat16_as_short(f2bf(a[j]));
    o[j + 4] = __bfloat16_as_short(f2bf(b[j]));
  }
  *(short8*)&dst[i] = o;
}

// ---------------------------------------------------------------------------
// Transpose f32 [K][N] -> bf16 [N][K], 64x64 tiles, 256 threads.
// ---------------------------------------------------------------------------
__global__ __launch_bounds__(256)
void transpose_cvt(const float* __restrict__ src,
                   __hip_bfloat16* __restrict__ dst,
                   int K, int N)
{
  __shared__ __hip_bfloat16 tile[64][72];
  const int tid = threadIdx.x;
  const int k0 = blockIdx.y * 64, n0 = blockIdx.x * 64;
  const int r = tid >> 3, c8 = tid & 7;
#pragma unroll
  for (int i = 0; i < 2; ++i) {
    int k = r + i * 32;
    f32x4 a = *(const f32x4*)&src[(size_t)(k0 + k) * N + n0 + c8 * 8];
    f32x4 b = *(const f32x4*)&src[(size_t)(k0 + k) * N + n0 + c8 * 8 + 4];
#pragma unroll
    for (int j = 0; j < 4; ++j) {
      tile[k][c8 * 8 + j]     = f2bf(a[j]);
      tile[k][c8 * 8 + 4 + j] = f2bf(b[j]);
    }
  }
  __syncthreads();
#pragma unroll
  for (int i = 0; i < 2; ++i) {
    int n = r + i * 32;
    short8 v;
#pragma unroll
    for (int j = 0; j < 8; ++j) v[j] = *(const short*)&tile[c8 * 8 + j][n];
    *(short8*)&dst[(size_t)(n0 + n) * K + k0 + c8 * 8] = v;
  }
}

// ---------------------------------------------------------------------------
// 256x256-tile QKV GEMM, BK=64; 512 threads = 8 waves (2M x 4N), per-wave
// 128x64 (FLOP:LDS-byte ratio 2x the 128-tile kernel). LDS 128KB full dbuf.
// 8 phases per iteration (2 K-tiles); per phase {ds_read; [stage unit];
// [gate]; s_barrier; setprio MFMA x16; s_barrier}.
// Staging units (4 loads/thread each): A1(T+1)@ph1, B0(T+2)@ph4,
// A0(T+2)@ph5, B1(T+3)@ph8. Gates: vmcnt(4) at ph4 (protects ph5's buf1
// reads: oldest 8 of 12 outstanding = B1(T+1),A1(T+1)) and at ph8 (protects
// next ph1's buf0 reads = B0,A0(T+2)). Never drains in steady state.
// Write hazards: each unit's dst region is read-complete (lgkm before MFMA)
// + barrier-separated before its stage issues.
// Epilogue scatters q/k/v^T. XCD column-partition swizzle.
// ---------------------------------------------------------------------------
__global__ __launch_bounds__(512, 2)
void gemm256_qkv(const __hip_bfloat16* __restrict__ A,
                 const __hip_bfloat16* __restrict__ Bt,
                 const float* __restrict__ bias,
                 __hip_bfloat16* __restrict__ qb,
                 __hip_bfloat16* __restrict__ kb,
                 __hip_bfloat16* __restrict__ vtb,
                 int M, int N, int K)
{
  __shared__ __hip_bfloat16 As[2][256 * 64];
  __shared__ __hip_bfloat16 Bs[2][256 * 64];

  const int tid = threadIdx.x, lane = tid & 63, wave = tid >> 6;
  const int wm = wave >> 2, wn = wave & 3;

  // XCD column-partition swizzle (grid = (N/256)*(M/256), 1-D)
  const int gx = N >> 8;
  const int cpx = gx >> 3;
  const int lin = blockIdx.x;
  const int xcd = lin & 7, t2 = lin >> 3;
  const int bx = xcd * cpx + (t2 % cpx);
  const int by = t2 / cpx;
  const int m0 = by * 256, n0 = bx * 256;

  const int fr = lane & 15, fq = lane >> 4;
  const int lrow = lane >> 3, lslot = lane & 7;

  // stage one 128-row unit (2 gload16/thread), linear LDS dest,
  // inverse-swizzled global source.
  auto stage = [&](const __hip_bfloat16* src, int srow0, int kc, char* dst128) {
#pragma unroll
    for (int r = 0; r < 2; ++r) {
      int rbase = r * 64 + wave * 8;
      int rr = rbase + lrow;
      int col = (lslot ^ (rr & 7)) << 3;
      gload16(&src[(size_t)(srow0 + rr) * K + kc + col], dst128 + rbase * 128);
    }
  };

  char* A0t = (char*)&As[0][0];  char* A1t = (char*)&As[1][0];
  char* B0t = (char*)&Bs[0][0];  char* B1t = (char*)&Bs[1][0];

  auto rdA = [&](const char* base, int mi, int kk) {   // mi 0..7
    int row = wm * 128 + mi * 16 + fr;
    int cb = (kk * 64 + fq * 16) ^ ((row & 7) << 4);
    return as_bf(*(const short8*)(base + row * 128 + cb));
  };
  auto rdB = [&](const char* base, int ni, int kk) {
    int row = wn * 64 + ni * 16 + fr;
    int cb = (kk * 64 + fq * 16) ^ ((row & 7) << 4);
    return as_bf(*(const short8*)(base + row * 128 + cb));
  };

  f32x4 acc[8][4] = {};
  const int kt = K / 64;          // 32
  const int nIt = kt / 2;         // 16

  // prologue: B0,A0(tile0) + B1(tile1) = 12 loads/thread
  stage(Bt, n0, 0, B0t); stage(Bt, n0 + 128, 0, B0t + 128 * 128);
  stage(A,  m0, 0, A0t); stage(A,  m0 + 128, 0, A0t + 128 * 128);
  stage(Bt, n0, 64, B1t); stage(Bt, n0 + 128, 64, B1t + 128 * 128);
  asm volatile("s_waitcnt vmcnt(4)" ::: "memory");   // B0,A0(t0) landed
  __builtin_amdgcn_s_barrier();

  for (int j = 0; j < nIt; ++j) {
    const int T = 2 * j;
    const bool pre = (j + 1 < nIt);
    const int kc1 = (T + 1) * 64, kc2 = (T + 2) * 64, kc3 = (T + 3) * 64;
    bf16x8 bfv[4], af[4];

#define QUAD(MB)                                                        \
    __builtin_amdgcn_s_setprio(1);                                      \
    _Pragma("unroll")                                                   \
    for (int mi = 0; mi < 4; ++mi)                                      \
      _Pragma("unroll")                                                 \
      for (int ni = 0; ni < 4; ++ni)                                    \
        acc[MB + mi][ni] = mfma16(af[mi], bfv[ni], acc[MB + mi][ni]);   \
    __builtin_amdgcn_s_setprio(0);

    // ---- ph1: buf0 B kk0 + A mi0-3 kk0; stage A1(T+1) ----
#pragma unroll
    for (int ni = 0; ni < 4; ++ni) bfv[ni] = rdB(B0t, ni, 0);
#pragma unroll
    for (int mi = 0; mi < 4; ++mi) af[mi] = rdA(A0t, mi, 0);
    stage(A, m0, kc1, A1t); stage(A, m0 + 128, kc1, A1t + 128 * 128);
    __builtin_amdgcn_s_barrier();
    QUAD(0)
    __builtin_amdgcn_s_barrier();

    // ---- ph2: A mi4-7 kk0 (reuse B kk0) ----
#pragma unroll
    for (int mi = 0; mi < 4; ++mi) af[mi] = rdA(A0t, mi + 4, 0);
    __builtin_amdgcn_s_barrier();
    QUAD(4)
    __builtin_amdgcn_s_barrier();

    // ---- ph3: buf0 B kk1 + A mi0-3 kk1 ----
#pragma unroll
    for (int ni = 0; ni < 4; ++ni) bfv[ni] = rdB(B0t, ni, 1);
#pragma unroll
    for (int mi = 0; mi < 4; ++mi) af[mi] = rdA(A0t, mi, 1);
    __builtin_amdgcn_s_barrier();
    QUAD(0)
    __builtin_amdgcn_s_barrier();

    // ---- ph4: A mi4-7 kk1; stage B0(T+2); gate for ph5's buf1 reads ----
#pragma unroll
    for (int mi = 0; mi < 4; ++mi) af[mi] = rdA(A0t, mi + 4, 1);
    if (pre) {
      stage(Bt, n0, kc2, B0t); stage(Bt, n0 + 128, kc2, B0t + 128 * 128);
      asm volatile("s_waitcnt vmcnt(4)" ::: "memory");  // B1,A1(T+1) landed
    } else {
      asm volatile("s_waitcnt vmcnt(0)" ::: "memory");
    }
    __builtin_amdgcn_s_barrier();
    QUAD(4)
    __builtin_amdgcn_s_barrier();

    // ---- ph5: buf1 B kk0 + A mi0-3 kk0; stage A0(T+2) ----
#pragma unroll
    for (int ni = 0; ni < 4; ++ni) bfv[ni] = rdB(B1t, ni, 0);
#pragma unroll
    for (int mi = 0; mi < 4; ++mi) af[mi] = rdA(A1t, mi, 0);
    if (pre) { stage(A, m0, kc2, A0t); stage(A, m0 + 128, kc2, A0t + 128 * 128); }
    __builtin_amdgcn_s_barrier();
    QUAD(0)
    __builtin_amdgcn_s_barrier();

    // ---- ph6: A mi4-7 kk0 ----
#pragma unroll
    for (int mi = 0; mi < 4; ++mi) af[mi] = rdA(A1t, mi + 4, 0);
    __builtin_amdgcn_s_barrier();
    QUAD(4)
    __builtin_amdgcn_s_barrier();

    // ---- ph7: buf1 B kk1 + A mi0-3 kk1 ----
#pragma unroll
    for (int ni = 0; ni < 4; ++ni) bfv[ni] = rdB(B1t, ni, 1);
#pragma unroll
    for (int mi = 0; mi < 4; ++mi) af[mi] = rdA(A1t, mi, 1);
    __builtin_amdgcn_s_barrier();
    QUAD(0)
    __builtin_amdgcn_s_barrier();

    // ---- ph8: A mi4-7 kk1; stage B1(T+3); gate for next ph1's buf0 reads ----
#pragma unroll
    for (int mi = 0; mi < 4; ++mi) af[mi] = rdA(A1t, mi + 4, 1);
    if (pre) {
      stage(Bt, n0, kc3, B1t); stage(Bt, n0 + 128, kc3, B1t + 128 * 128);
      asm volatile("s_waitcnt vmcnt(4)" ::: "memory");  // B0,A0(T+2) landed
    }
    __builtin_amdgcn_s_barrier();
    QUAD(4)
    __builtin_amdgcn_s_barrier();
#undef QUAD
  }

  // epilogue: scatter to q/k/v^T. Per-ni (head, qkv-type) is uniform.
#pragma unroll
  for (int ni = 0; ni < 4; ++ni) {
    const int nb = n0 + wn * 64 + ni * 16;       // 16-aligned
    const int h = nb / 384;
    const int rb = nb - h * 384;
    const int t3 = rb >> 7;
    const int dloc = (rb & 127) + fr;
    const float bv = bias[nb + fr];
#pragma unroll
    for (int mi = 0; mi < 8; ++mi) {
      const int mbase = m0 + wm * 128 + mi * 16 + fq * 4;
#pragma unroll
      for (int jj = 0; jj < 4; ++jj) {
        const int m = mbase + jj;
        const int b = m >> 11, s = m & 2047;
        const int bh = b * 16 + h;
        const float v = acc[mi][ni][jj] + bv;
        if (t3 == 0)      qb[((size_t)bh * 2048 + s) * 128 + dloc] = f2bf(v);
        else if (t3 == 1) kb[((size_t)bh * 2048 + s) * 128 + dloc] = f2bf(v);
        else              vtb[((size_t)bh * 128 + dloc) * 2048 + s] = f2bf(v);
      }
    }
  }
}

// ---------------------------------------------------------------------------
// Deep-pipelined 128x256 GEMM (r7 structure) — used for the dense projection.
// ---------------------------------------------------------------------------
__global__ __launch_bounds__(512, 2)
void gemm8p(const __hip_bfloat16* __restrict__ A,
            const __hip_bfloat16* __restrict__ Bt,
            const float* __restrict__ bias,
            float* __restrict__ C,
            int M, int N, int K)
{
  __shared__ __hip_bfloat16 As[2][128 * 64];
  __shared__ __hip_bfloat16 Bs[2][256 * 64];

  const int tid = threadIdx.x, lane = tid & 63, wave = tid >> 6;
  const int wm = wave >> 2, wn = wave & 3;

  const int gx = N >> 8;
  const int cpx = gx >> 3;
  const int lin = blockIdx.x;
  const int xcd = lin & 7, t2 = lin >> 3;
  const int bx = xcd * cpx + (t2 % cpx);
  const int by = t2 / cpx;
  const int m0 = by * 128, n0 = bx * 256;

  const int fr = lane & 15, fq = lane >> 4;
  const int lrow = lane >> 3, lslot = lane & 7;

  auto stage = [&](const __hip_bfloat16* src, int srow0, int kc, char* dstTile) {
#pragma unroll
    for (int r = 0; r < 2; ++r) {
      int rbase = r * 64 + wave * 8;
      int rr = rbase + lrow;
      int col = (lslot ^ (rr & 7)) << 3;
      gload16(&src[(size_t)(srow0 + rr) * K + kc + col], dstTile + rbase * 128);
    }
  };

  char* A0 = (char*)&As[0][0];  char* A1 = (char*)&As[1][0];
  char* B0 = (char*)&Bs[0][0];  char* B1 = (char*)&Bs[1][0];

  auto rdA = [&](const char* base, int mi, int kk) {
    int row = wm * 64 + mi * 16 + fr;
    int cb = (kk * 64 + fq * 16) ^ ((row & 7) << 4);
    return as_bf(*(const short8*)(base + row * 128 + cb));
  };
  auto rdB = [&](const char* base, int ni, int kk) {
    int row = wn * 64 + ni * 16 + fr;
    int cb = (kk * 64 + fq * 16) ^ ((row & 7) << 4);
    return as_bf(*(const short8*)(base + row * 128 + cb));
  };

  f32x4 acc[4][4] = {};
  const int kt = K / 64;
  const int nIt = kt / 2;

  stage(Bt, n0,       0, B0); stage(Bt, n0 + 128,  0, B0 + 128 * 128);
  stage(A,  m0,       0, A0);
  stage(Bt, n0,      64, B1); stage(Bt, n0 + 128, 64, B1 + 128 * 128);
  stage(A,  m0,      64, A1);
  asm volatile("s_waitcnt vmcnt(6)" ::: "memory");
  __builtin_amdgcn_s_barrier();

  for (int j = 0; j < nIt; ++j) {
    const int T = 2 * j;
    const bool last = (j == nIt - 1);
    const int kc2 = (T + 2) * 64, kc3 = (T + 3) * 64;
    bf16x8 bfr[4][2], afr[2][2];

#pragma unroll
    for (int ni = 0; ni < 4; ++ni) { bfr[ni][0] = rdB(B0, ni, 0); bfr[ni][1] = rdB(B0, ni, 1); }
#pragma unroll
    for (int mi = 0; mi < 2; ++mi) { afr[mi][0] = rdA(A0, mi, 0); afr[mi][1] = rdA(A0, mi, 1); }
    __builtin_amdgcn_s_barrier();
    __builtin_amdgcn_s_setprio(1);
#pragma unroll
    for (int kk = 0; kk < 2; ++kk)
#pragma unroll
      for (int mi = 0; mi < 2; ++mi)
#pragma unroll
        for (int ni = 0; ni < 4; ++ni)
          acc[mi][ni] = mfma16(afr[mi][kk], bfr[ni][kk], acc[mi][ni]);
    __builtin_amdgcn_s_setprio(0);
    __builtin_amdgcn_s_barrier();

#pragma unroll
    for (int mi = 0; mi < 2; ++mi) { afr[mi][0] = rdA(A0, mi + 2, 0); afr[mi][1] = rdA(A0, mi + 2, 1); }
    if (!last) {
      stage(Bt, n0, kc2, B0);
      asm volatile("s_waitcnt vmcnt(2)" ::: "memory");
    } else {
      asm volatile("s_waitcnt vmcnt(0)" ::: "memory");
    }
    __builtin_amdgcn_s_barrier();
    __builtin_amdgcn_s_setprio(1);
#pragma unroll
    for (int kk = 0; kk < 2; ++kk)
#pragma unroll
      for (int mi = 0; mi < 2; ++mi)
#pragma unroll
        for (int ni = 0; ni < 4; ++ni)
          acc[mi + 2][ni] = mfma16(afr[mi][kk], bfr[ni][kk], acc[mi + 2][ni]);
    __builtin_amdgcn_s_setprio(0);
    __builtin_amdgcn_s_barrier();

#pragma unroll
    for (int ni = 0; ni < 4; ++ni) { bfr[ni][0] = rdB(B1, ni, 0); bfr[ni][1] = rdB(B1, ni, 1); }
#pragma unroll
    for (int mi = 0; mi < 2; ++mi) { afr[mi][0] = rdA(A1, mi, 0); afr[mi][1] = rdA(A1, mi, 1); }
    if (!last) {
      stage(Bt, n0 + 128, kc2, B0 + 128 * 128);
      stage(A,  m0,       kc2, A0);
    }
    __builtin_amdgcn_s_barrier();
    __builtin_amdgcn_s_setprio(1);
#pragma unroll
    for (int kk = 0; kk < 2; ++kk)
#pragma unroll
      for (int mi = 0; mi < 2; ++mi)
#pragma unroll
        for (int ni = 0; ni < 4; ++ni)
          acc[mi][ni] = mfma16(afr[mi][kk], bfr[ni][kk], acc[mi][ni]);
    __builtin_amdgcn_s_setprio(0);
    __builtin_amdgcn_s_barrier();

#pragma unroll
    for (int mi = 0; mi < 2; ++mi) { afr[mi][0] = rdA(A1, mi + 2, 0); afr[mi][1] = rdA(A1, mi + 2, 1); }
    if (!last) {
      stage(Bt, n0,       kc3, B1);
      stage(Bt, n0 + 128, kc3, B1 + 128 * 128);
      asm volatile("s_waitcnt vmcnt(4)" ::: "memory");
    } else {
      asm volatile("s_waitcnt vmcnt(0)" ::: "memory");
    }
    __builtin_amdgcn_s_barrier();
    __builtin_amdgcn_s_setprio(1);
#pragma unroll
    for (int kk = 0; kk < 2; ++kk)
#pragma unroll
      for (int mi = 0; mi < 2; ++mi)
#pragma unroll
        for (int ni = 0; ni < 4; ++ni)
          acc[mi + 2][ni] = mfma16(afr[mi][kk], bfr[ni][kk], acc[mi + 2][ni]);
    __builtin_amdgcn_s_setprio(0);
    if (!last) stage(A, m0, kc3, A1);
    __builtin_amdgcn_s_barrier();
  }

#pragma unroll
  for (int ni = 0; ni < 4; ++ni) {
    int n = n0 + wn * 64 + ni * 16 + fr;
    float bv = bias[n];
#pragma unroll
    for (int mi = 0; mi < 4; ++mi) {
      int mbase = m0 + wm * 64 + mi * 16 + fq * 4;
#pragma unroll
      for (int jj = 0; jj < 4; ++jj)
        C[(size_t)(mbase + jj) * N + n] = acc[mi][ni][jj] + bv;
    }
  }
}

// ---------------------------------------------------------------------------
// Causal flash attention (heavy-first, double-buffered, setprio).
// ---------------------------------------------------------------------------
__global__ __launch_bounds__(256)
void attn_kernel(const __hip_bfloat16* __restrict__ qb,
                 const __hip_bfloat16* __restrict__ kb,
                 const __hip_bfloat16* __restrict__ vtb,
                 __hip_bfloat16* __restrict__ ctx)
{
  __shared__ __hip_bfloat16 Ks[2][64 * 128];
  __shared__ __hip_bfloat16 Vts[2][128 * 64];
  __shared__ __hip_bfloat16 Ps[4][16 * 64];

  const int tid = threadIdx.x, lane = tid & 63, wave = tid >> 6;
  const int fr = lane & 15, fq = lane >> 4;
  const int blk = blockIdx.x;
  const int qi = 31 - (blk >> 5);
  const int bh = blk & 31;
  const int q0 = qi * 64;

  bf16x8 qf[4];
  const int qrow = q0 + wave * 16 + fr;
#pragma unroll
  for (int kf = 0; kf < 4; ++kf)
    qf[kf] = as_bf(*(const short8*)&qb[((size_t)bh * 2048 + qrow) * 128 + kf * 32 + fq * 8]);

  f32x4 acco[8] = {};
  float m_run[4] = {-1e30f, -1e30f, -1e30f, -1e30f};
  float l_run[4] = {0.f, 0.f, 0.f, 0.f};

  char* Pb = (char*)&Ps[wave][0];
  const int nt = qi + 1;

  auto STAGE = [&](int t, int buf) {
    const int k0t = t * 64;
#pragma unroll
    for (int i = 0; i < 4; ++i) {
      int c = wave * 4 + i;
      int kv = c * 4 + fq;
      int cb = (fr * 16) ^ ((kv & 7) << 4);
      gload16(&kb[((size_t)bh * 2048 + k0t + kv) * 128 + (cb >> 1)], &Ks[buf][c * 512]);
    }
#pragma unroll
    for (int i = 0; i < 4; ++i) {
      int c = wave * 4 + i;
      int d = c * 8 + (lane >> 3);
      int cb = ((lane & 7) * 16) ^ ((d & 7) << 4);
      gload16(&vtb[((size_t)bh * 128 + d) * 2048 + k0t + (cb >> 1)], &Vts[buf][c * 512]);
    }
  };

  STAGE(0, 0);
  __syncthreads();

  int cur = 0;
  for (int t = 0; t < nt; ++t) {
    if (t + 1 < nt) STAGE(t + 1, cur ^ 1);
    const char* Kb = (const char*)&Ks[cur][0];
    const char* Vb = (const char*)&Vts[cur][0];
    const int k0 = t * 64;

    f32x4 sacc[4] = {};
    __builtin_amdgcn_s_setprio(1);
#pragma unroll
    for (int kf = 0; kf < 4; ++kf) {
#pragma unroll
      for (int ni = 0; ni < 4; ++ni) {
        int kv = ni * 16 + fr;
        int cb = (kf * 64 + fq * 16) ^ ((kv & 7) << 4);
        bf16x8 kfr = as_bf(*(const short8*)(Kb + kv * 256 + cb));
        sacc[ni] = mfma16(qf[kf], kfr, sacc[ni]);
      }
    }
    __builtin_amdgcn_s_setprio(0);

    const float scale = 0.088388347648318447f;
    float sv[4][4];
    float rmax[4] = {-1e30f, -1e30f, -1e30f, -1e30f};
#pragma unroll
    for (int ni = 0; ni < 4; ++ni) {
      int kv_g = k0 + ni * 16 + fr;
#pragma unroll
      for (int j = 0; j < 4; ++j) {
        int q_g = q0 + wave * 16 + fq * 4 + j;
        float s = sacc[ni][j] * scale;
        if (kv_g > q_g) s = -10000.f;
        sv[ni][j] = s;
        rmax[j] = fmaxf(rmax[j], s);
      }
    }
#pragma unroll
    for (int off = 1; off < 16; off <<= 1)
#pragma unroll
      for (int j = 0; j < 4; ++j)
        rmax[j] = fmaxf(rmax[j], __shfl_xor(rmax[j], off));

    float alpha[4], rsum[4];
#pragma unroll
    for (int j = 0; j < 4; ++j) {
      float mn = fmaxf(m_run[j], rmax[j]);
      alpha[j] = __expf(m_run[j] - mn);
      m_run[j] = mn;
      rsum[j] = 0.f;
    }
#pragma unroll
    for (int ni = 0; ni < 4; ++ni) {
#pragma unroll
      for (int j = 0; j < 4; ++j) {
        float p = __expf(sv[ni][j] - m_run[j]);
        rsum[j] += p;
        int prow = fq * 4 + j;
        int cbw = ((ni * 16 + fr) * 2) ^ ((prow & 7) << 4);
        *(__hip_bfloat16*)(Pb + prow * 128 + cbw) = f2bf(p);
      }
    }
#pragma unroll
    for (int off = 1; off < 16; off <<= 1)
#pragma unroll
      for (int j = 0; j < 4; ++j)
        rsum[j] += __shfl_xor(rsum[j], off);
#pragma unroll
    for (int j = 0; j < 4; ++j)
      l_run[j] = l_run[j] * alpha[j] + rsum[j];

#pragma unroll
    for (int nd = 0; nd < 8; ++nd)
#pragma unroll
      for (int j = 0; j < 4; ++j)
        acco[nd][j] *= alpha[j];

    asm volatile("s_waitcnt lgkmcnt(0)" ::: "memory");
    __builtin_amdgcn_sched_barrier(0);

    __builtin_amdgcn_s_setprio(1);
#pragma unroll
    for (int kf2 = 0; kf2 < 2; ++kf2) {
      int cbp = (kf2 * 64 + fq * 16) ^ ((fr & 7) << 4);
      bf16x8 pa = as_bf(*(const short8*)(Pb + fr * 128 + cbp));
#pragma unroll
      for (int nd = 0; nd < 8; ++nd) {
        int d = nd * 16 + fr;
        int cbv = (kf2 * 64 + fq * 16) ^ ((d & 7) << 4);
        bf16x8 vfr = as_bf(*(const short8*)(Vb + d * 128 + cbv));
        acco[nd] = mfma16(pa, vfr, acco[nd]);
      }
    }
    __builtin_amdgcn_s_setprio(0);
    __syncthreads();
    cur ^= 1;
  }

  const int b = bh >> 4, h = bh & 15;
#pragma unroll
  for (int j = 0; j < 4; ++j) {
    float inv = 1.f / l_run[j];
    int s = q0 + wave * 16 + fq * 4 + j;
#pragma unroll
    for (int nd = 0; nd < 8; ++nd) {
      int d = nd * 16 + fr;
      ctx[(((size_t)b * 2048 + s) * 16 + h) * 128 + d] = f2bf(acco[nd][j] * inv);
    }
  }
}

// ---------------------------------------------------------------------------
extern "C" void kernel_launch(void* const* d_in, const int* in_sizes, int n_in,
                              void* d_out, int out_size, void* d_ws, size_t ws_size,
                              hipStream_t stream)
{
  (void)in_sizes; (void)n_in; (void)out_size; (void)ws_size;
  const float* x       = (const float*)d_in[0];
  const float* w_qkv   = (const float*)d_in[1];
  const float* b_qkv   = (const float*)d_in[2];
  const float* w_dense = (const float*)d_in[3];
  const float* b_dense = (const float*)d_in[4];
  float* out = (float*)d_out;

  char* ws = (char*)d_ws;
  __hip_bfloat16* x_bf     = (__hip_bfloat16*)(ws);                  // 16MB
  __hip_bfloat16* wqkv_t   = (__hip_bfloat16*)(ws + 16777216);       // 24MB
  __hip_bfloat16* wdense_t = (__hip_bfloat16*)(ws + 41943040);       // 8MB
  __hip_bfloat16* qb       = (__hip_bfloat16*)(ws + 50331648);       // 16MB
  __hip_bfloat16* kb       = (__hip_bfloat16*)(ws + 67108864);       // 16MB
  __hip_bfloat16* vtb      = (__hip_bfloat16*)(ws + 83886080);       // 16MB
  __hip_bfloat16* ctx      = (__hip_bfloat16*)(ws + 100663296);      // 16MB

  cvt_f32_bf16<<<4096, 256, 0, stream>>>(x, x_bf, 4096 * 2048);
  transpose_cvt<<<dim3(96, 32), 256, 0, stream>>>(w_qkv, wqkv_t, 2048, 6144);
  transpose_cvt<<<dim3(32, 32), 256, 0, stream>>>(w_dense, wdense_t, 2048, 2048);
  // QKV: grid (4096/256)*(6144/256) = 16*24 = 384
  gemm256_qkv<<<384, 512, 0, stream>>>(x_bf, wqkv_t, b_qkv,
                                       qb, kb, vtb, 4096, 6144, 2048);
  attn_kernel<<<1024, 256, 0, stream>>>(qb, kb, vtb, ctx);
  // dense: grid (4096/128)*(2048/256) = 32*8 = 256
  gemm8p<<<256, 512, 0, stream>>>(ctx, wdense_t, b_dense, out,
                                  4096, 2048, 2048);
}

// Round 9
// 287.153 us; speedup vs baseline: 1.0227x; 1.0227x over previous
//
#include <hip/hip_runtime.h>
#include <hip/hip_bf16.h>
#include <stdint.h>

#define DEV __device__ __forceinline__

typedef __attribute__((ext_vector_type(8))) short short8;
typedef __attribute__((ext_vector_type(8))) __bf16 bf16x8;
typedef __attribute__((ext_vector_type(4))) float f32x4;

typedef const __attribute__((address_space(1))) uint32_t gu32;
typedef __attribute__((address_space(3))) uint32_t lu32;

DEV void gload16(const void* g, void* l) {
  __builtin_amdgcn_global_load_lds((gu32*)g, (lu32*)l, 16, 0, 0);
}

DEV f32x4 mfma16(bf16x8 a, bf16x8 b, f32x4 c) {
  return __builtin_amdgcn_mfma_f32_16x16x32_bf16(a, b, c, 0, 0, 0);
}

DEV __hip_bfloat16 f2bf(float x) { return __float2bfloat16(x); }
DEV bf16x8 as_bf(short8 v) { union { short8 s; bf16x8 b; } u; u.s = v; return u.b; }

// ---------------------------------------------------------------------------
// f32 -> bf16 elementwise convert (n multiple of 8).
// ---------------------------------------------------------------------------
__global__ __launch_bounds__(256)
void cvt_f32_bf16(const float* __restrict__ src, __hip_bfloat16* __restrict__ dst, int n)
{
  int i = (blockIdx.x * 256 + threadIdx.x) * 8;
  if (i >= n) return;
  f32x4 a = *(const f32x4*)&src[i];
  f32x4 b = *(const f32x4*)&src[i + 4];
  short8 o;
#pragma unroll
  for (int j = 0; j < 4; ++j) {
    o[j]     = __bfloat16_as_short(f2bf(a[j]));
    o[j + 4] = __bfloat16_as_short(f2bf(b[j]));
  }
  *(short8*)&dst[i] = o;
}

// ---------------------------------------------------------------------------
// Transpose f32 [K][N] -> bf16 [N][K], 64x64 tiles, 256 threads.
// ---------------------------------------------------------------------------
__global__ __launch_bounds__(256)
void transpose_cvt(const float* __restrict__ src,
                   __hip_bfloat16* __restrict__ dst,
                   int K, int N)
{
  __shared__ __hip_bfloat16 tile[64][72];
  const int tid = threadIdx.x;
  const int k0 = blockIdx.y * 64, n0 = blockIdx.x * 64;
  const int r = tid >> 3, c8 = tid & 7;
#pragma unroll
  for (int i = 0; i < 2; ++i) {
    int k = r + i * 32;
    f32x4 a = *(const f32x4*)&src[(size_t)(k0 + k) * N + n0 + c8 * 8];
    f32x4 b = *(const f32x4*)&src[(size_t)(k0 + k) * N + n0 + c8 * 8 + 4];
#pragma unroll
    for (int j = 0; j < 4; ++j) {
      tile[k][c8 * 8 + j]     = f2bf(a[j]);
      tile[k][c8 * 8 + 4 + j] = f2bf(b[j]);
    }
  }
  __syncthreads();
#pragma unroll
  for (int i = 0; i < 2; ++i) {
    int n = r + i * 32;
    short8 v;
#pragma unroll
    for (int j = 0; j < 8; ++j) v[j] = *(const short*)&tile[c8 * 8 + j][n];
    *(short8*)&dst[(size_t)(n0 + n) * K + k0 + c8 * 8] = v;
  }
}

// ---------------------------------------------------------------------------
// QKV GEMM: BM=128, BN=384, BK=64; 512 threads = 8 waves (2M x 4N),
// per-wave 64x96 (FLOP/LDS-byte = 38.4 vs 32 for 128x256). Grid 512 = 2
// tail-free rounds. LDS 128KB full dbuf. 8 phases / 2 K-tiles; per phase
// {ds_read; [stage]; [gate]; barrier; setprio 12xMFMA; barrier}.
// Load groups: A(T+1)[2]@ph1, B(T+2)[6]@ph4, A(T+2)[2]@ph5, B(T+3)[6]@ph8.
// Gates: vmcnt(6)@ph4 (waits B(T+1)+A(T+1) of 14 outstanding) and
// vmcnt(6)@ph8 (waits B(T+2)+A(T+2)). Steady in-flight 8-14 loads.
// Epilogue scatters q/k/v^T (head = nb/384, BN=384 = one head's qkv).
// ---------------------------------------------------------------------------
__global__ __launch_bounds__(512, 2)
void gemm_qkv384(const __hip_bfloat16* __restrict__ A,
                 const __hip_bfloat16* __restrict__ Bt,
                 const float* __restrict__ bias,
                 __hip_bfloat16* __restrict__ qb,
                 __hip_bfloat16* __restrict__ kb,
                 __hip_bfloat16* __restrict__ vtb,
                 int M, int N, int K)
{
  __shared__ __hip_bfloat16 As[2][128 * 64];   // 32KB
  __shared__ __hip_bfloat16 Bs[2][384 * 64];   // 96KB

  const int tid = threadIdx.x, lane = tid & 63, wave = tid >> 6;
  const int wm = wave >> 2, wn = wave & 3;

  // XCD partition: 2 N-cols per XCD (B panel 3MB fits 4MB L2)
  const int lin = blockIdx.x;
  const int xcd = lin & 7, idx = lin >> 3;       // idx in [0,64)
  const int bx = xcd * 2 + (idx >> 5);           // [0,16)
  const int by = idx & 31;                       // [0,32)
  const int m0 = by * 128, n0 = bx * 384;

  const int fr = lane & 15, fq = lane >> 4;
  const int lrow = lane >> 3, lslot = lane & 7;

  // stage one 128-row unit (2 gload16/thread)
  auto stage = [&](const __hip_bfloat16* src, int srow0, int kc, char* dst128) {
#pragma unroll
    for (int r = 0; r < 2; ++r) {
      int rbase = r * 64 + wave * 8;
      int rr = rbase + lrow;
      int col = (lslot ^ (rr & 7)) << 3;
      gload16(&src[(size_t)(srow0 + rr) * K + kc + col], dst128 + rbase * 128);
    }
  };

  char* A0t = (char*)&As[0][0];  char* A1t = (char*)&As[1][0];
  char* B0t = (char*)&Bs[0][0];  char* B1t = (char*)&Bs[1][0];

  auto stageB = [&](int kc, char* Bdst) {       // 3 calls = 6 loads
    stage(Bt, n0,       kc, Bdst);
    stage(Bt, n0 + 128, kc, Bdst + 128 * 128);
    stage(Bt, n0 + 256, kc, Bdst + 256 * 128);
  };

  auto rdA = [&](const char* base, int mi, int kk) {   // mi 0..3
    int row = wm * 64 + mi * 16 + fr;
    int cb = (kk * 64 + fq * 16) ^ ((row & 7) << 4);
    return as_bf(*(const short8*)(base + row * 128 + cb));
  };
  auto rdB = [&](const char* base, int ni, int kk) {   // ni 0..5
    int row = wn * 96 + ni * 16 + fr;
    int cb = (kk * 64 + fq * 16) ^ ((row & 7) << 4);
    return as_bf(*(const short8*)(base + row * 128 + cb));
  };

  f32x4 acc[4][6] = {};
  const int nIt = K / 128;      // 16

  bf16x8 bfv[6], af[2];
  auto CLUST = [&](int mb) {
    __builtin_amdgcn_s_setprio(1);
#pragma unroll
    for (int mi = 0; mi < 2; ++mi)
#pragma unroll
      for (int ni = 0; ni < 6; ++ni)
        acc[mb + mi][ni] = mfma16(af[mi], bfv[ni], acc[mb + mi][ni]);
    __builtin_amdgcn_s_setprio(0);
  };

  // prologue: B(0), A(0), B(1)  (14 loads/thread)
  stageB(0, B0t);
  stage(A, m0, 0, A0t);
  stageB(64, B1t);
  asm volatile("s_waitcnt vmcnt(6)" ::: "memory");   // B(0),A(0) landed
  __builtin_amdgcn_s_barrier();

  for (int j = 0; j < nIt; ++j) {
    const int T = 2 * j;
    const bool pre = (j + 1 < nIt);
    const int kc1 = (T + 1) * 64, kc2 = (T + 2) * 64, kc3 = (T + 3) * 64;

    // ph1: buf0 B kk0 + A mi01 kk0; stage A(T+1)
#pragma unroll
    for (int ni = 0; ni < 6; ++ni) bfv[ni] = rdB(B0t, ni, 0);
    af[0] = rdA(A0t, 0, 0); af[1] = rdA(A0t, 1, 0);
    stage(A, m0, kc1, A1t);
    __builtin_amdgcn_s_barrier();
    CLUST(0);
    __builtin_amdgcn_s_barrier();

    // ph2: A mi23 kk0
    af[0] = rdA(A0t, 2, 0); af[1] = rdA(A0t, 3, 0);
    __builtin_amdgcn_s_barrier();
    CLUST(2);
    __builtin_amdgcn_s_barrier();

    // ph3: buf0 B kk1 + A mi01 kk1
#pragma unroll
    for (int ni = 0; ni < 6; ++ni) bfv[ni] = rdB(B0t, ni, 1);
    af[0] = rdA(A0t, 0, 1); af[1] = rdA(A0t, 1, 1);
    __builtin_amdgcn_s_barrier();
    CLUST(0);
    __builtin_amdgcn_s_barrier();

    // ph4: A mi23 kk1; stage B(T+2); gate (B(T+1),A(T+1) landed)
    af[0] = rdA(A0t, 2, 1); af[1] = rdA(A0t, 3, 1);
    if (pre) {
      stageB(kc2, B0t);
      asm volatile("s_waitcnt vmcnt(6)" ::: "memory");
    } else {
      asm volatile("s_waitcnt vmcnt(0)" ::: "memory");
    }
    __builtin_amdgcn_s_barrier();
    CLUST(2);
    __builtin_amdgcn_s_barrier();

    // ph5: buf1 B kk0 + A mi01 kk0; stage A(T+2)
#pragma unroll
    for (int ni = 0; ni < 6; ++ni) bfv[ni] = rdB(B1t, ni, 0);
    af[0] = rdA(A1t, 0, 0); af[1] = rdA(A1t, 1, 0);
    if (pre) stage(A, m0, kc2, A0t);
    __builtin_amdgcn_s_barrier();
    CLUST(0);
    __builtin_amdgcn_s_barrier();

    // ph6: A mi23 kk0
    af[0] = rdA(A1t, 2, 0); af[1] = rdA(A1t, 3, 0);
    __builtin_amdgcn_s_barrier();
    CLUST(2);
    __builtin_amdgcn_s_barrier();

    // ph7: buf1 B kk1 + A mi01 kk1
#pragma unroll
    for (int ni = 0; ni < 6; ++ni) bfv[ni] = rdB(B1t, ni, 1);
    af[0] = rdA(A1t, 0, 1); af[1] = rdA(A1t, 1, 1);
    __builtin_amdgcn_s_barrier();
    CLUST(0);
    __builtin_amdgcn_s_barrier();

    // ph8: A mi23 kk1; stage B(T+3); gate (B(T+2),A(T+2) landed)
    af[0] = rdA(A1t, 2, 1); af[1] = rdA(A1t, 3, 1);
    if (pre) {
      stageB(kc3, B1t);
      asm volatile("s_waitcnt vmcnt(6)" ::: "memory");
    }
    __builtin_amdgcn_s_barrier();
    CLUST(2);
    __builtin_amdgcn_s_barrier();
  }

  // epilogue: scatter q/k/v^T. head h = nb/384; per-ni type uniform.
#pragma unroll
  for (int ni = 0; ni < 6; ++ni) {
    const int nb = n0 + wn * 96 + ni * 16;       // 16-aligned
    const int h = nb / 384;
    const int rb = nb - h * 384;
    const int t3 = rb >> 7;
    const int dloc = (rb & 127) + fr;
    const float bv = bias[nb + fr];
#pragma unroll
    for (int mi = 0; mi < 4; ++mi) {
      const int mbase = m0 + wm * 64 + mi * 16 + fq * 4;
#pragma unroll
      for (int jj = 0; jj < 4; ++jj) {
        const int m = mbase + jj;
        const int b = m >> 11, s = m & 2047;
        const int bh = b * 16 + h;
        const float v = acc[mi][ni][jj] + bv;
        if (t3 == 0)      qb[((size_t)bh * 2048 + s) * 128 + dloc] = f2bf(v);
        else if (t3 == 1) kb[((size_t)bh * 2048 + s) * 128 + dloc] = f2bf(v);
        else              vtb[((size_t)bh * 128 + dloc) * 2048 + s] = f2bf(v);
      }
    }
  }
}

// ---------------------------------------------------------------------------
// Deep-pipelined 128x256 GEMM (r7 structure) — dense projection. Grid 256.
// ---------------------------------------------------------------------------
__global__ __launch_bounds__(512, 2)
void gemm8p(const __hip_bfloat16* __restrict__ A,
            const __hip_bfloat16* __restrict__ Bt,
            const float* __restrict__ bias,
            float* __restrict__ C,
            int M, int N, int K)
{
  __shared__ __hip_bfloat16 As[2][128 * 64];
  __shared__ __hip_bfloat16 Bs[2][256 * 64];

  const int tid = threadIdx.x, lane = tid & 63, wave = tid >> 6;
  const int wm = wave >> 2, wn = wave & 3;

  const int gx = N >> 8;
  const int cpx = gx >> 3;
  const int lin = blockIdx.x;
  const int xcd = lin & 7, t2 = lin >> 3;
  const int bx = xcd * cpx + (t2 % cpx);
  const int by = t2 / cpx;
  const int m0 = by * 128, n0 = bx * 256;

  const int fr = lane & 15, fq = lane >> 4;
  const int lrow = lane >> 3, lslot = lane & 7;

  auto stage = [&](const __hip_bfloat16* src, int srow0, int kc, char* dstTile) {
#pragma unroll
    for (int r = 0; r < 2; ++r) {
      int rbase = r * 64 + wave * 8;
      int rr = rbase + lrow;
      int col = (lslot ^ (rr & 7)) << 3;
      gload16(&src[(size_t)(srow0 + rr) * K + kc + col], dstTile + rbase * 128);
    }
  };

  char* A0 = (char*)&As[0][0];  char* A1 = (char*)&As[1][0];
  char* B0 = (char*)&Bs[0][0];  char* B1 = (char*)&Bs[1][0];

  auto rdA = [&](const char* base, int mi, int kk) {
    int row = wm * 64 + mi * 16 + fr;
    int cb = (kk * 64 + fq * 16) ^ ((row & 7) << 4);
    return as_bf(*(const short8*)(base + row * 128 + cb));
  };
  auto rdB = [&](const char* base, int ni, int kk) {
    int row = wn * 64 + ni * 16 + fr;
    int cb = (kk * 64 + fq * 16) ^ ((row & 7) << 4);
    return as_bf(*(const short8*)(base + row * 128 + cb));
  };

  f32x4 acc[4][4] = {};
  const int kt = K / 64;
  const int nIt = kt / 2;

  stage(Bt, n0,       0, B0); stage(Bt, n0 + 128,  0, B0 + 128 * 128);
  stage(A,  m0,       0, A0);
  stage(Bt, n0,      64, B1); stage(Bt, n0 + 128, 64, B1 + 128 * 128);
  stage(A,  m0,      64, A1);
  asm volatile("s_waitcnt vmcnt(6)" ::: "memory");
  __builtin_amdgcn_s_barrier();

  for (int j = 0; j < nIt; ++j) {
    const int T = 2 * j;
    const bool last = (j == nIt - 1);
    const int kc2 = (T + 2) * 64, kc3 = (T + 3) * 64;
    bf16x8 bfr[4][2], afr[2][2];

#pragma unroll
    for (int ni = 0; ni < 4; ++ni) { bfr[ni][0] = rdB(B0, ni, 0); bfr[ni][1] = rdB(B0, ni, 1); }
#pragma unroll
    for (int mi = 0; mi < 2; ++mi) { afr[mi][0] = rdA(A0, mi, 0); afr[mi][1] = rdA(A0, mi, 1); }
    __builtin_amdgcn_s_barrier();
    __builtin_amdgcn_s_setprio(1);
#pragma unroll
    for (int kk = 0; kk < 2; ++kk)
#pragma unroll
      for (int mi = 0; mi < 2; ++mi)
#pragma unroll
        for (int ni = 0; ni < 4; ++ni)
          acc[mi][ni] = mfma16(afr[mi][kk], bfr[ni][kk], acc[mi][ni]);
    __builtin_amdgcn_s_setprio(0);
    __builtin_amdgcn_s_barrier();

#pragma unroll
    for (int mi = 0; mi < 2; ++mi) { afr[mi][0] = rdA(A0, mi + 2, 0); afr[mi][1] = rdA(A0, mi + 2, 1); }
    if (!last) {
      stage(Bt, n0, kc2, B0);
      asm volatile("s_waitcnt vmcnt(2)" ::: "memory");
    } else {
      asm volatile("s_waitcnt vmcnt(0)" ::: "memory");
    }
    __builtin_amdgcn_s_barrier();
    __builtin_amdgcn_s_setprio(1);
#pragma unroll
    for (int kk = 0; kk < 2; ++kk)
#pragma unroll
      for (int mi = 0; mi < 2; ++mi)
#pragma unroll
        for (int ni = 0; ni < 4; ++ni)
          acc[mi + 2][ni] = mfma16(afr[mi][kk], bfr[ni][kk], acc[mi + 2][ni]);
    __builtin_amdgcn_s_setprio(0);
    __builtin_amdgcn_s_barrier();

#pragma unroll
    for (int ni = 0; ni < 4; ++ni) { bfr[ni][0] = rdB(B1, ni, 0); bfr[ni][1] = rdB(B1, ni, 1); }
#pragma unroll
    for (int mi = 0; mi < 2; ++mi) { afr[mi][0] = rdA(A1, mi, 0); afr[mi][1] = rdA(A1, mi, 1); }
    if (!last) {
      stage(Bt, n0 + 128, kc2, B0 + 128 * 128);
      stage(A,  m0,       kc2, A0);
    }
    __builtin_amdgcn_s_barrier();
    __builtin_amdgcn_s_setprio(1);
#pragma unroll
    for (int kk = 0; kk < 2; ++kk)
#pragma unroll
      for (int mi = 0; mi < 2; ++mi)
#pragma unroll
        for (int ni = 0; ni < 4; ++ni)
          acc[mi][ni] = mfma16(afr[mi][kk], bfr[ni][kk], acc[mi][ni]);
    __builtin_amdgcn_s_setprio(0);
    __builtin_amdgcn_s_barrier();

#pragma unroll
    for (int mi = 0; mi < 2; ++mi) { afr[mi][0] = rdA(A1, mi + 2, 0); afr[mi][1] = rdA(A1, mi + 2, 1); }
    if (!last) {
      stage(Bt, n0,       kc3, B1);
      stage(Bt, n0 + 128, kc3, B1 + 128 * 128);
      asm volatile("s_waitcnt vmcnt(4)" ::: "memory");
    } else {
      asm volatile("s_waitcnt vmcnt(0)" ::: "memory");
    }
    __builtin_amdgcn_s_barrier();
    __builtin_amdgcn_s_setprio(1);
#pragma unroll
    for (int kk = 0; kk < 2; ++kk)
#pragma unroll
      for (int mi = 0; mi < 2; ++mi)
#pragma unroll
        for (int ni = 0; ni < 4; ++ni)
          acc[mi + 2][ni] = mfma16(afr[mi][kk], bfr[ni][kk], acc[mi + 2][ni]);
    __builtin_amdgcn_s_setprio(0);
    if (!last) stage(A, m0, kc3, A1);
    __builtin_amdgcn_s_barrier();
  }

#pragma unroll
  for (int ni = 0; ni < 4; ++ni) {
    int n = n0 + wn * 64 + ni * 16 + fr;
    float bv = bias[n];
#pragma unroll
    for (int mi = 0; mi < 4; ++mi) {
      int mbase = m0 + wm * 64 + mi * 16 + fq * 4;
#pragma unroll
      for (int jj = 0; jj < 4; ++jj)
        C[(size_t)(mbase + jj) * N + n] = acc[mi][ni][jj] + bv;
    }
  }
}

// ---------------------------------------------------------------------------
// Causal flash attention: QBLK=128 (8 waves, 512 threads), KV tiles of 64,
// double-buffered K/V, heavy-first, setprio. LDS 80KB -> 2 blocks/CU.
// ---------------------------------------------------------------------------
__global__ __launch_bounds__(512)
void attn_kernel(const __hip_bfloat16* __restrict__ qb,
                 const __hip_bfloat16* __restrict__ kb,
                 const __hip_bfloat16* __restrict__ vtb,
                 __hip_bfloat16* __restrict__ ctx)
{
  __shared__ __hip_bfloat16 Ks[2][64 * 128];    // 32KB
  __shared__ __hip_bfloat16 Vts[2][128 * 64];   // 32KB
  __shared__ __hip_bfloat16 Ps[8][16 * 64];     // 16KB

  const int tid = threadIdx.x, lane = tid & 63, wave = tid >> 6;
  const int fr = lane & 15, fq = lane >> 4;
  const int blk = blockIdx.x;
  const int qi = 15 - (blk >> 5);      // heavy first
  const int bh = blk & 31;
  const int q0 = qi * 128;

  bf16x8 qf[4];
  const int qrow = q0 + wave * 16 + fr;
#pragma unroll
  for (int kf = 0; kf < 4; ++kf)
    qf[kf] = as_bf(*(const short8*)&qb[((size_t)bh * 2048 + qrow) * 128 + kf * 32 + fq * 8]);

  f32x4 acco[8] = {};
  float m_run[4] = {-1e30f, -1e30f, -1e30f, -1e30f};
  float l_run[4] = {0.f, 0.f, 0.f, 0.f};

  char* Pb = (char*)&Ps[wave][0];
  const int nt = 2 * qi + 2;

  auto STAGE = [&](int t, int buf) {
    const int k0t = t * 64;
#pragma unroll
    for (int i = 0; i < 2; ++i) {
      int c = wave * 2 + i;                 // 16 chunks x 1KB
      int kv = c * 4 + fq;
      int cb = (fr * 16) ^ ((kv & 7) << 4);
      gload16(&kb[((size_t)bh * 2048 + k0t + kv) * 128 + (cb >> 1)], &Ks[buf][c * 512]);
    }
#pragma unroll
    for (int i = 0; i < 2; ++i) {
      int c = wave * 2 + i;
      int d = c * 8 + (lane >> 3);
      int cb = ((lane & 7) * 16) ^ ((d & 7) << 4);
      gload16(&vtb[((size_t)bh * 128 + d) * 2048 + k0t + (cb >> 1)], &Vts[buf][c * 512]);
    }
  };

  STAGE(0, 0);
  __syncthreads();

  int cur = 0;
  for (int t = 0; t < nt; ++t) {
    if (t + 1 < nt) STAGE(t + 1, cur ^ 1);
    const char* Kb = (const char*)&Ks[cur][0];
    const char* Vb = (const char*)&Vts[cur][0];
    const int k0 = t * 64;

    f32x4 sacc[4] = {};
    __builtin_amdgcn_s_setprio(1);
#pragma unroll
    for (int kf = 0; kf < 4; ++kf) {
#pragma unroll
      for (int ni = 0; ni < 4; ++ni) {
        int kv = ni * 16 + fr;
        int cb = (kf * 64 + fq * 16) ^ ((kv & 7) << 4);
        bf16x8 kfr = as_bf(*(const short8*)(Kb + kv * 256 + cb));
        sacc[ni] = mfma16(qf[kf], kfr, sacc[ni]);
      }
    }
    __builtin_amdgcn_s_setprio(0);

    const float scale = 0.088388347648318447f;
    float sv[4][4];
    float rmax[4] = {-1e30f, -1e30f, -1e30f, -1e30f};
#pragma unroll
    for (int ni = 0; ni < 4; ++ni) {
      int kv_g = k0 + ni * 16 + fr;
#pragma unroll
      for (int j = 0; j < 4; ++j) {
        int q_g = q0 + wave * 16 + fq * 4 + j;
        float s = sacc[ni][j] * scale;
        if (kv_g > q_g) s = -10000.f;
        sv[ni][j] = s;
        rmax[j] = fmaxf(rmax[j], s);
      }
    }
#pragma unroll
    for (int off = 1; off < 16; off <<= 1)
#pragma unroll
      for (int j = 0; j < 4; ++j)
        rmax[j] = fmaxf(rmax[j], __shfl_xor(rmax[j], off));

    float alpha[4], rsum[4];
#pragma unroll
    for (int j = 0; j < 4; ++j) {
      float mn = fmaxf(m_run[j], rmax[j]);
      alpha[j] = __expf(m_run[j] - mn);
      m_run[j] = mn;
      rsum[j] = 0.f;
    }
#pragma unroll
    for (int ni = 0; ni < 4; ++ni) {
#pragma unroll
      for (int j = 0; j < 4; ++j) {
        float p = __expf(sv[ni][j] - m_run[j]);
        rsum[j] += p;
        int prow = fq * 4 + j;
        int cbw = ((ni * 16 + fr) * 2) ^ ((prow & 7) << 4);
        *(__hip_bfloat16*)(Pb + prow * 128 + cbw) = f2bf(p);
      }
    }
#pragma unroll
    for (int off = 1; off < 16; off <<= 1)
#pragma unroll
      for (int j = 0; j < 4; ++j)
        rsum[j] += __shfl_xor(rsum[j], off);
#pragma unroll
    for (int j = 0; j < 4; ++j)
      l_run[j] = l_run[j] * alpha[j] + rsum[j];

#pragma unroll
    for (int nd = 0; nd < 8; ++nd)
#pragma unroll
      for (int j = 0; j < 4; ++j)
        acco[nd][j] *= alpha[j];

    asm volatile("s_waitcnt lgkmcnt(0)" ::: "memory");
    __builtin_amdgcn_sched_barrier(0);

    __builtin_amdgcn_s_setprio(1);
#pragma unroll
    for (int kf2 = 0; kf2 < 2; ++kf2) {
      int cbp = (kf2 * 64 + fq * 16) ^ ((fr & 7) << 4);
      bf16x8 pa = as_bf(*(const short8*)(Pb + fr * 128 + cbp));
#pragma unroll
      for (int nd = 0; nd < 8; ++nd) {
        int d = nd * 16 + fr;
        int cbv = (kf2 * 64 + fq * 16) ^ ((d & 7) << 4);
        bf16x8 vfr = as_bf(*(const short8*)(Vb + d * 128 + cbv));
        acco[nd] = mfma16(pa, vfr, acco[nd]);
      }
    }
    __builtin_amdgcn_s_setprio(0);
    __syncthreads();
    cur ^= 1;
  }

  const int b = bh >> 4, h = bh & 15;
#pragma unroll
  for (int j = 0; j < 4; ++j) {
    float inv = 1.f / l_run[j];
    int s = q0 + wave * 16 + fq * 4 + j;
#pragma unroll
    for (int nd = 0; nd < 8; ++nd) {
      int d = nd * 16 + fr;
      ctx[(((size_t)b * 2048 + s) * 16 + h) * 128 + d] = f2bf(acco[nd][j] * inv);
    }
  }
}

// ---------------------------------------------------------------------------
extern "C" void kernel_launch(void* const* d_in, const int* in_sizes, int n_in,
                              void* d_out, int out_size, void* d_ws, size_t ws_size,
                              hipStream_t stream)
{
  (void)in_sizes; (void)n_in; (void)out_size; (void)ws_size;
  const float* x       = (const float*)d_in[0];
  const float* w_qkv   = (const float*)d_in[1];
  const float* b_qkv   = (const float*)d_in[2];
  const float* w_dense = (const float*)d_in[3];
  const float* b_dense = (const float*)d_in[4];
  float* out = (float*)d_out;

  char* ws = (char*)d_ws;
  __hip_bfloat16* x_bf     = (__hip_bfloat16*)(ws);                  // 16MB
  __hip_bfloat16* wqkv_t   = (__hip_bfloat16*)(ws + 16777216);       // 24MB
  __hip_bfloat16* wdense_t = (__hip_bfloat16*)(ws + 41943040);       // 8MB
  __hip_bfloat16* qb       = (__hip_bfloat16*)(ws + 50331648);       // 16MB
  __hip_bfloat16* kb       = (__hip_bfloat16*)(ws + 67108864);       // 16MB
  __hip_bfloat16* vtb      = (__hip_bfloat16*)(ws + 83886080);       // 16MB
  __hip_bfloat16* ctx      = (__hip_bfloat16*)(ws + 100663296);      // 16MB

  cvt_f32_bf16<<<4096, 256, 0, stream>>>(x, x_bf, 4096 * 2048);
  transpose_cvt<<<dim3(96, 32), 256, 0, stream>>>(w_qkv, wqkv_t, 2048, 6144);
  transpose_cvt<<<dim3(32, 32), 256, 0, stream>>>(w_dense, wdense_t, 2048, 2048);
  // QKV: grid (4096/128)*(6144/384) = 32*16 = 512 = 2 tail-free rounds
  gemm_qkv384<<<512, 512, 0, stream>>>(x_bf, wqkv_t, b_qkv,
                                       qb, kb, vtb, 4096, 6144, 2048);
  // attn: 16 q-tiles of 128 x 32 bh = 512 blocks, 2/CU resident
  attn_kernel<<<512, 512, 0, stream>>>(qb, kb, vtb, ctx);
  // dense: grid (4096/128)*(2048/256) = 256 = 1 round
  gemm8p<<<256, 512, 0, stream>>>(ctx, wdense_t, b_dense, out,
                                  4096, 2048, 2048);
}

// Round 11
// 266.071 us; speedup vs baseline: 1.1037x; 1.0792x over previous
//
#include <hip/hip_runtime.h>
#include <hip/hip_bf16.h>
#include <stdint.h>

#define DEV __device__ __forceinline__

typedef __attribute__((ext_vector_type(8))) short short8;
typedef __attribute__((ext_vector_type(8))) __bf16 bf16x8;
typedef __attribute__((ext_vector_type(4))) float f32x4;

typedef const __attribute__((address_space(1))) uint32_t gu32;
typedef __attribute__((address_space(3))) uint32_t lu32;

DEV void gload16(const void* g, void* l) {
  __builtin_amdgcn_global_load_lds((gu32*)g, (lu32*)l, 16, 0, 0);
}

DEV f32x4 mfma16(bf16x8 a, bf16x8 b, f32x4 c) {
  return __builtin_amdgcn_mfma_f32_16x16x32_bf16(a, b, c, 0, 0, 0);
}

DEV __hip_bfloat16 f2bf(float x) { return __float2bfloat16(x); }
DEV bf16x8 as_bf(short8 v) { union { short8 s; bf16x8 b; } u; u.s = v; return u.b; }

// ---------------------------------------------------------------------------
// Merged prepro: [0,4096) cvt x; [4096,7168) transpose w_qkv; rest w_dense.
// ---------------------------------------------------------------------------
__global__ __launch_bounds__(256)
void prep_kernel(const float* __restrict__ x, __hip_bfloat16* __restrict__ x_bf,
                 const float* __restrict__ w_qkv, __hip_bfloat16* __restrict__ wqkv_t,
                 const float* __restrict__ w_dense, __hip_bfloat16* __restrict__ wdense_t)
{
  __shared__ __hip_bfloat16 tile[64][72];
  const int tid = threadIdx.x;
  const int blk = blockIdx.x;

  if (blk < 4096) {
    int i = (blk * 256 + tid) * 8;
    f32x4 a = *(const f32x4*)&x[i];
    f32x4 b = *(const f32x4*)&x[i + 4];
    short8 o;
#pragma unroll
    for (int j = 0; j < 4; ++j) {
      o[j]     = __bfloat16_as_short(f2bf(a[j]));
      o[j + 4] = __bfloat16_as_short(f2bf(b[j]));
    }
    *(short8*)&x_bf[i] = o;
    return;
  }

  const float* src; __hip_bfloat16* dst; int K, N, bx, by;
  if (blk < 4096 + 3072) {
    int bb = blk - 4096; src = w_qkv; dst = wqkv_t; K = 2048; N = 6144;
    bx = bb % 96; by = bb / 96;
  } else {
    int bb = blk - 7168; src = w_dense; dst = wdense_t; K = 2048; N = 2048;
    bx = bb % 32; by = bb / 32;
  }
  const int k0 = by * 64, n0 = bx * 64;
  const int r = tid >> 3, c8 = tid & 7;
#pragma unroll
  for (int i = 0; i < 2; ++i) {
    int k = r + i * 32;
    f32x4 a = *(const f32x4*)&src[(size_t)(k0 + k) * N + n0 + c8 * 8];
    f32x4 b = *(const f32x4*)&src[(size_t)(k0 + k) * N + n0 + c8 * 8 + 4];
#pragma unroll
    for (int j = 0; j < 4; ++j) {
      tile[k][c8 * 8 + j]     = f2bf(a[j]);
      tile[k][c8 * 8 + 4 + j] = f2bf(b[j]);
    }
  }
  __syncthreads();
#pragma unroll
  for (int i = 0; i < 2; ++i) {
    int n = r + i * 32;
    short8 v;
#pragma unroll
    for (int j = 0; j < 8; ++j) v[j] = *(const short*)&tile[c8 * 8 + j][n];
    *(short8*)&dst[(size_t)(n0 + n) * K + k0 + c8 * 8] = v;
  }
}

// ---------------------------------------------------------------------------
// QKV GEMM: BM=128, BN=192, BK=64; 512 threads = 8 waves (2M x 4N),
// per-wave 64x48. LDS 80KB full dbuf -> 2 BLOCKS/CU (cross-block wave
// overlap). Grid 1024 = 2 tail-free rounds.
// RACE-FREE gate discipline (r8 pattern): every vmcnt gate immediately
// precedes a barrier; the reads it protects are in the NEXT phase.
//  p1: rd buf0.B(kk0+kk1->regs)+A kk0; stage A(T+1)->buf1.A; bar; MFMA; bar
//  p2: rd buf0.A kk1; stage B(T+2)->buf0.B; vmcnt(3); bar; MFMA; bar
//  p3: rd buf1.B(both)+A kk0;            stage A(T+2)->buf0.A; bar; MFMA; bar
//  p4: rd buf1.A kk1; stage B(T+3)->buf1.B; vmcnt(3); bar; MFMA; bar
// Invariant entering each iter: outstanding = B(odd tile)[3]. Gates leave 3
// in flight (never drain except last iter). Every staged region's previous
// reads are register-complete + barrier-separated.
// ---------------------------------------------------------------------------
__global__ __launch_bounds__(512, 4)
void gemm192_qkv(const __hip_bfloat16* __restrict__ A,
                 const __hip_bfloat16* __restrict__ Bt,
                 const float* __restrict__ bias,
                 __hip_bfloat16* __restrict__ qb,
                 __hip_bfloat16* __restrict__ kb,
                 __hip_bfloat16* __restrict__ vtb,
                 int M, int N, int K)
{
  __shared__ __hip_bfloat16 As[2][128 * 64];   // 32KB
  __shared__ __hip_bfloat16 Bs[2][192 * 64];   // 48KB

  const int tid = threadIdx.x, lane = tid & 63, wave = tid >> 6;
  const int wm = wave >> 2, wn = wave & 3;

  // XCD partition: 4 consecutive N-cols per XCD
  const int lin = blockIdx.x;
  const int xcd = lin & 7, t2 = lin >> 3;
  const int bx = xcd * 4 + (t2 & 3);
  const int by = t2 >> 2;
  const int m0 = by * 128, n0 = bx * 192;

  const int fr = lane & 15, fq = lane >> 4;
  const int lrow = lane >> 3, lslot = lane & 7;

  auto stageA = [&](int kc, char* dst) {       // 2 loads: 128 rows
#pragma unroll
    for (int r = 0; r < 2; ++r) {
      int rbase = r * 64 + wave * 8;
      int rr = rbase + lrow;
      int col = (lslot ^ (rr & 7)) << 3;
      gload16(&A[(size_t)(m0 + rr) * K + kc + col], dst + rbase * 128);
    }
  };
  auto stageB = [&](int kc, char* dst) {       // 3 loads: 192 rows
#pragma unroll
    for (int r = 0; r < 3; ++r) {
      int rbase = r * 64 + wave * 8;
      int rr = rbase + lrow;
      int col = (lslot ^ (rr & 7)) << 3;
      gload16(&Bt[(size_t)(n0 + rr) * K + kc + col], dst + rbase * 128);
    }
  };

  char* A0t = (char*)&As[0][0];  char* A1t = (char*)&As[1][0];
  char* B0t = (char*)&Bs[0][0];  char* B1t = (char*)&Bs[1][0];

  auto rdA = [&](const char* base, int mi, int kk) {   // mi 0..3
    int row = wm * 64 + mi * 16 + fr;
    int cb = (kk * 64 + fq * 16) ^ ((row & 7) << 4);
    return as_bf(*(const short8*)(base + row * 128 + cb));
  };
  auto rdB = [&](const char* base, int ni, int kk) {   // ni 0..2
    int row = wn * 48 + ni * 16 + fr;
    int cb = (kk * 64 + fq * 16) ^ ((row & 7) << 4);
    return as_bf(*(const short8*)(base + row * 128 + cb));
  };

  f32x4 acc[4][3] = {};
  const int nIt = K / 128;      // 16

  bf16x8 bk0[3], bk1[3], af[4];
  auto CLUST = [&](bf16x8* bv) {
    __builtin_amdgcn_s_setprio(1);
#pragma unroll
    for (int mi = 0; mi < 4; ++mi)
#pragma unroll
      for (int ni = 0; ni < 3; ++ni)
        acc[mi][ni] = mfma16(af[mi], bv[ni], acc[mi][ni]);
    __builtin_amdgcn_s_setprio(0);
  };

  // prologue: B(0),A(0)->buf0, B(1)->buf1.B; gate tile0; barrier.
  stageB(0, B0t); stageA(0, A0t); stageB(64, B1t);
  asm volatile("s_waitcnt vmcnt(3)" ::: "memory");   // B(0),A(0) landed
  __builtin_amdgcn_s_barrier();
  // invariant: outstanding = B(1)[3]

  for (int j = 0; j < nIt; ++j) {
    const int T = 2 * j;
    const bool pre = (j + 1 < nIt);
    const int kc1 = (T + 1) * 64, kc2 = (T + 2) * 64, kc3 = (T + 3) * 64;

    // ---- p1: read buf0.B both kk + A kk0; stage A(T+1)->buf1.A ----
#pragma unroll
    for (int ni = 0; ni < 3; ++ni) { bk0[ni] = rdB(B0t, ni, 0); bk1[ni] = rdB(B0t, ni, 1); }
#pragma unroll
    for (int mi = 0; mi < 4; ++mi) af[mi] = rdA(A0t, mi, 0);
    stageA(kc1, A1t);                              // outstanding 3+2=5
    __builtin_amdgcn_s_barrier();
    CLUST(bk0);
    __builtin_amdgcn_s_barrier();

    // ---- p2: read buf0.A kk1; stage B(T+2)->buf0.B; gate(T+1) ----
#pragma unroll
    for (int mi = 0; mi < 4; ++mi) af[mi] = rdA(A0t, mi, 1);
    if (pre) {
      stageB(kc2, B0t);                            // outstanding 8
      asm volatile("s_waitcnt vmcnt(3)" ::: "memory");  // B(T+1),A(T+1) landed
    } else {
      asm volatile("s_waitcnt vmcnt(0)" ::: "memory");
    }
    __builtin_amdgcn_s_barrier();
    CLUST(bk1);
    __builtin_amdgcn_s_barrier();

    // ---- p3: read buf1.B both kk + A kk0; stage A(T+2)->buf0.A ----
#pragma unroll
    for (int ni = 0; ni < 3; ++ni) { bk0[ni] = rdB(B1t, ni, 0); bk1[ni] = rdB(B1t, ni, 1); }
#pragma unroll
    for (int mi = 0; mi < 4; ++mi) af[mi] = rdA(A1t, mi, 0);
    if (pre) stageA(kc2, A0t);                     // outstanding 5
    __builtin_amdgcn_s_barrier();
    CLUST(bk0);
    __builtin_amdgcn_s_barrier();

    // ---- p4: read buf1.A kk1; stage B(T+3)->buf1.B; gate(T+2) ----
#pragma unroll
    for (int mi = 0; mi < 4; ++mi) af[mi] = rdA(A1t, mi, 1);
    if (pre) {
      stageB(kc3, B1t);                            // outstanding 8
      asm volatile("s_waitcnt vmcnt(3)" ::: "memory");  // B(T+2),A(T+2) landed
    }
    __builtin_amdgcn_s_barrier();
    CLUST(bk1);
    __builtin_amdgcn_s_barrier();
  }

  // epilogue: scatter q/k/v^T. Per-ni (head, qkv-type) uniform (16 | 128).
#pragma unroll
  for (int ni = 0; ni < 3; ++ni) {
    const int nb = n0 + wn * 48 + ni * 16;
    const int h = nb / 384;
    const int rb = nb - h * 384;
    const int t3 = rb >> 7;
    const int dloc = (rb & 127) + fr;
    const float bv = bias[nb + fr];
#pragma unroll
    for (int mi = 0; mi < 4; ++mi) {
      const int mbase = m0 + wm * 64 + mi * 16 + fq * 4;
#pragma unroll
      for (int jj = 0; jj < 4; ++jj) {
        const int m = mbase + jj;
        const int b = m >> 11, s = m & 2047;
        const int bh = b * 16 + h;
        const float v = acc[mi][ni][jj] + bv;
        if (t3 == 0)      qb[((size_t)bh * 2048 + s) * 128 + dloc] = f2bf(v);
        else if (t3 == 1) kb[((size_t)bh * 2048 + s) * 128 + dloc] = f2bf(v);
        else              vtb[((size_t)bh * 128 + dloc) * 2048 + s] = f2bf(v);
      }
    }
  }
}

// ---------------------------------------------------------------------------
// Deep-pipelined 128x256 GEMM (r7 structure) — dense projection. Grid 256.
// ---------------------------------------------------------------------------
__global__ __launch_bounds__(512, 2)
void gemm8p(const __hip_bfloat16* __restrict__ A,
            const __hip_bfloat16* __restrict__ Bt,
            const float* __restrict__ bias,
            float* __restrict__ C,
            int M, int N, int K)
{
  __shared__ __hip_bfloat16 As[2][128 * 64];
  __shared__ __hip_bfloat16 Bs[2][256 * 64];

  const int tid = threadIdx.x, lane = tid & 63, wave = tid >> 6;
  const int wm = wave >> 2, wn = wave & 3;

  const int gx = N >> 8;
  const int cpx = gx >> 3;
  const int lin = blockIdx.x;
  const int xcd = lin & 7, t2 = lin >> 3;
  const int bx = xcd * cpx + (t2 % cpx);
  const int by = t2 / cpx;
  const int m0 = by * 128, n0 = bx * 256;

  const int fr = lane & 15, fq = lane >> 4;
  const int lrow = lane >> 3, lslot = lane & 7;

  auto stage = [&](const __hip_bfloat16* src, int srow0, int kc, char* dstTile) {
#pragma unroll
    for (int r = 0; r < 2; ++r) {
      int rbase = r * 64 + wave * 8;
      int rr = rbase + lrow;
      int col = (lslot ^ (rr & 7)) << 3;
      gload16(&src[(size_t)(srow0 + rr) * K + kc + col], dstTile + rbase * 128);
    }
  };

  char* A0 = (char*)&As[0][0];  char* A1 = (char*)&As[1][0];
  char* B0 = (char*)&Bs[0][0];  char* B1 = (char*)&Bs[1][0];

  auto rdA = [&](const char* base, int mi, int kk) {
    int row = wm * 64 + mi * 16 + fr;
    int cb = (kk * 64 + fq * 16) ^ ((row & 7) << 4);
    return as_bf(*(const short8*)(base + row * 128 + cb));
  };
  auto rdB = [&](const char* base, int ni, int kk) {
    int row = wn * 64 + ni * 16 + fr;
    int cb = (kk * 64 + fq * 16) ^ ((row & 7) << 4);
    return as_bf(*(const short8*)(base + row * 128 + cb));
  };

  f32x4 acc[4][4] = {};
  const int kt = K / 64;
  const int nIt = kt / 2;

  stage(Bt, n0,       0, B0); stage(Bt, n0 + 128,  0, B0 + 128 * 128);
  stage(A,  m0,       0, A0);
  stage(Bt, n0,      64, B1); stage(Bt, n0 + 128, 64, B1 + 128 * 128);
  stage(A,  m0,      64, A1);
  asm volatile("s_waitcnt vmcnt(6)" ::: "memory");
  __builtin_amdgcn_s_barrier();

  for (int j = 0; j < nIt; ++j) {
    const int T = 2 * j;
    const bool last = (j == nIt - 1);
    const int kc2 = (T + 2) * 64, kc3 = (T + 3) * 64;
    bf16x8 bfr[4][2], afr[2][2];

#pragma unroll
    for (int ni = 0; ni < 4; ++ni) { bfr[ni][0] = rdB(B0, ni, 0); bfr[ni][1] = rdB(B0, ni, 1); }
#pragma unroll
    for (int mi = 0; mi < 2; ++mi) { afr[mi][0] = rdA(A0, mi, 0); afr[mi][1] = rdA(A0, mi, 1); }
    __builtin_amdgcn_s_barrier();
    __builtin_amdgcn_s_setprio(1);
#pragma unroll
    for (int kk = 0; kk < 2; ++kk)
#pragma unroll
      for (int mi = 0; mi < 2; ++mi)
#pragma unroll
        for (int ni = 0; ni < 4; ++ni)
          acc[mi][ni] = mfma16(afr[mi][kk], bfr[ni][kk], acc[mi][ni]);
    __builtin_amdgcn_s_setprio(0);
    __builtin_amdgcn_s_barrier();

#pragma unroll
    for (int mi = 0; mi < 2; ++mi) { afr[mi][0] = rdA(A0, mi + 2, 0); afr[mi][1] = rdA(A0, mi + 2, 1); }
    if (!last) {
      stage(Bt, n0, kc2, B0);
      asm volatile("s_waitcnt vmcnt(2)" ::: "memory");
    } else {
      asm volatile("s_waitcnt vmcnt(0)" ::: "memory");
    }
    __builtin_amdgcn_s_barrier();
    __builtin_amdgcn_s_setprio(1);
#pragma unroll
    for (int kk = 0; kk < 2; ++kk)
#pragma unroll
      for (int mi = 0; mi < 2; ++mi)
#pragma unroll
        for (int ni = 0; ni < 4; ++ni)
          acc[mi + 2][ni] = mfma16(afr[mi][kk], bfr[ni][kk], acc[mi + 2][ni]);
    __builtin_amdgcn_s_setprio(0);
    __builtin_amdgcn_s_barrier();

#pragma unroll
    for (int ni = 0; ni < 4; ++ni) { bfr[ni][0] = rdB(B1, ni, 0); bfr[ni][1] = rdB(B1, ni, 1); }
#pragma unroll
    for (int mi = 0; mi < 2; ++mi) { afr[mi][0] = rdA(A1, mi, 0); afr[mi][1] = rdA(A1, mi, 1); }
    if (!last) {
      stage(Bt, n0 + 128, kc2, B0 + 128 * 128);
      stage(A,  m0,       kc2, A0);
    }
    __builtin_amdgcn_s_barrier();
    __builtin_amdgcn_s_setprio(1);
#pragma unroll
    for (int kk = 0; kk < 2; ++kk)
#pragma unroll
      for (int mi = 0; mi < 2; ++mi)
#pragma unroll
        for (int ni = 0; ni < 4; ++ni)
          acc[mi][ni] = mfma16(afr[mi][kk], bfr[ni][kk], acc[mi][ni]);
    __builtin_amdgcn_s_setprio(0);
    __builtin_amdgcn_s_barrier();

#pragma unroll
    for (int mi = 0; mi < 2; ++mi) { afr[mi][0] = rdA(A1, mi + 2, 0); afr[mi][1] = rdA(A1, mi + 2, 1); }
    if (!last) {
      stage(Bt, n0,       kc3, B1);
      stage(Bt, n0 + 128, kc3, B1 + 128 * 128);
      asm volatile("s_waitcnt vmcnt(4)" ::: "memory");
    } else {
      asm volatile("s_waitcnt vmcnt(0)" ::: "memory");
    }
    __builtin_amdgcn_s_barrier();
    __builtin_amdgcn_s_setprio(1);
#pragma unroll
    for (int kk = 0; kk < 2; ++kk)
#pragma unroll
      for (int mi = 0; mi < 2; ++mi)
#pragma unroll
        for (int ni = 0; ni < 4; ++ni)
          acc[mi + 2][ni] = mfma16(afr[mi][kk], bfr[ni][kk], acc[mi + 2][ni]);
    __builtin_amdgcn_s_setprio(0);
    if (!last) stage(A, m0, kc3, A1);
    __builtin_amdgcn_s_barrier();
  }

#pragma unroll
  for (int ni = 0; ni < 4; ++ni) {
    int n = n0 + wn * 64 + ni * 16 + fr;
    float bv = bias[n];
#pragma unroll
    for (int mi = 0; mi < 4; ++mi) {
      int mbase = m0 + wm * 64 + mi * 16 + fq * 4;
#pragma unroll
      for (int jj = 0; jj < 4; ++jj)
        C[(size_t)(mbase + jj) * N + n] = acc[mi][ni][jj] + bv;
    }
  }
}

// ---------------------------------------------------------------------------
// Causal flash attention (QBLK=64, heavy-first, double-buffered, setprio).
// ---------------------------------------------------------------------------
__global__ __launch_bounds__(256)
void attn_kernel(const __hip_bfloat16* __restrict__ qb,
                 const __hip_bfloat16* __restrict__ kb,
                 const __hip_bfloat16* __restrict__ vtb,
                 __hip_bfloat16* __restrict__ ctx)
{
  __shared__ __hip_bfloat16 Ks[2][64 * 128];
  __shared__ __hip_bfloat16 Vts[2][128 * 64];
  __shared__ __hip_bfloat16 Ps[4][16 * 64];

  const int tid = threadIdx.x, lane = tid & 63, wave = tid >> 6;
  const int fr = lane & 15, fq = lane >> 4;
  const int blk = blockIdx.x;
  const int qi = 31 - (blk >> 5);
  const int bh = blk & 31;
  const int q0 = qi * 64;

  bf16x8 qf[4];
  const int qrow = q0 + wave * 16 + fr;
#pragma unroll
  for (int kf = 0; kf < 4; ++kf)
    qf[kf] = as_bf(*(const short8*)&qb[((size_t)bh * 2048 + qrow) * 128 + kf * 32 + fq * 8]);

  f32x4 acco[8] = {};
  float m_run[4] = {-1e30f, -1e30f, -1e30f, -1e30f};
  float l_run[4] = {0.f, 0.f, 0.f, 0.f};

  char* Pb = (char*)&Ps[wave][0];
  const int nt = qi + 1;

  auto STAGE = [&](int t, int buf) {
    const int k0t = t * 64;
#pragma unroll
    for (int i = 0; i < 4; ++i) {
      int c = wave * 4 + i;
      int kv = c * 4 + fq;
      int cb = (fr * 16) ^ ((kv & 7) << 4);
      gload16(&kb[((size_t)bh * 2048 + k0t + kv) * 128 + (cb >> 1)], &Ks[buf][c * 512]);
    }
#pragma unroll
    for (int i = 0; i < 4; ++i) {
      int c = wave * 4 + i;
      int d = c * 8 + (lane >> 3);
      int cb = ((lane & 7) * 16) ^ ((d & 7) << 4);
      gload16(&vtb[((size_t)bh * 128 + d) * 2048 + k0t + (cb >> 1)], &Vts[buf][c * 512]);
    }
  };

  STAGE(0, 0);
  __syncthreads();

  int cur = 0;
  for (int t = 0; t < nt; ++t) {
    if (t + 1 < nt) STAGE(t + 1, cur ^ 1);
    const char* Kb = (const char*)&Ks[cur][0];
    const char* Vb = (const char*)&Vts[cur][0];
    const int k0 = t * 64;

    f32x4 sacc[4] = {};
    __builtin_amdgcn_s_setprio(1);
#pragma unroll
    for (int kf = 0; kf < 4; ++kf) {
#pragma unroll
      for (int ni = 0; ni < 4; ++ni) {
        int kv = ni * 16 + fr;
        int cb = (kf * 64 + fq * 16) ^ ((kv & 7) << 4);
        bf16x8 kfr = as_bf(*(const short8*)(Kb + kv * 256 + cb));
        sacc[ni] = mfma16(qf[kf], kfr, sacc[ni]);
      }
    }
    __builtin_amdgcn_s_setprio(0);

    const float scale = 0.088388347648318447f;
    float sv[4][4];
    float rmax[4] = {-1e30f, -1e30f, -1e30f, -1e30f};
#pragma unroll
    for (int ni = 0; ni < 4; ++ni) {
      int kv_g = k0 + ni * 16 + fr;
#pragma unroll
      for (int j = 0; j < 4; ++j) {
        int q_g = q0 + wave * 16 + fq * 4 + j;
        float s = sacc[ni][j] * scale;
        if (kv_g > q_g) s = -10000.f;
        sv[ni][j] = s;
        rmax[j] = fmaxf(rmax[j], s);
      }
    }
#pragma unroll
    for (int off = 1; off < 16; off <<= 1)
#pragma unroll
      for (int j = 0; j < 4; ++j)
        rmax[j] = fmaxf(rmax[j], __shfl_xor(rmax[j], off));

    float alpha[4], rsum[4];
#pragma unroll
    for (int j = 0; j < 4; ++j) {
      float mn = fmaxf(m_run[j], rmax[j]);
      alpha[j] = __expf(m_run[j] - mn);
      m_run[j] = mn;
      rsum[j] = 0.f;
    }
#pragma unroll
    for (int ni = 0; ni < 4; ++ni) {
#pragma unroll
      for (int j = 0; j < 4; ++j) {
        float p = __expf(sv[ni][j] - m_run[j]);
        rsum[j] += p;
        int prow = fq * 4 + j;
        int cbw = ((ni * 16 + fr) * 2) ^ ((prow & 7) << 4);
        *(__hip_bfloat16*)(Pb + prow * 128 + cbw) = f2bf(p);
      }
    }
#pragma unroll
    for (int off = 1; off < 16; off <<= 1)
#pragma unroll
      for (int j = 0; j < 4; ++j)
        rsum[j] += __shfl_xor(rsum[j], off);
#pragma unroll
    for (int j = 0; j < 4; ++j)
      l_run[j] = l_run[j] * alpha[j] + rsum[j];

#pragma unroll
    for (int nd = 0; nd < 8; ++nd)
#pragma unroll
      for (int j = 0; j < 4; ++j)
        acco[nd][j] *= alpha[j];

    asm volatile("s_waitcnt lgkmcnt(0)" ::: "memory");
    __builtin_amdgcn_sched_barrier(0);

    __builtin_amdgcn_s_setprio(1);
#pragma unroll
    for (int kf2 = 0; kf2 < 2; ++kf2) {
      int cbp = (kf2 * 64 + fq * 16) ^ ((fr & 7) << 4);
      bf16x8 pa = as_bf(*(const short8*)(Pb + fr * 128 + cbp));
#pragma unroll
      for (int nd = 0; nd < 8; ++nd) {
        int d = nd * 16 + fr;
        int cbv = (kf2 * 64 + fq * 16) ^ ((d & 7) << 4);
        bf16x8 vfr = as_bf(*(const short8*)(Vb + d * 128 + cbv));
        acco[nd] = mfma16(pa, vfr, acco[nd]);
      }
    }
    __builtin_amdgcn_s_setprio(0);
    __syncthreads();
    cur ^= 1;
  }

  const int b = bh >> 4, h = bh & 15;
#pragma unroll
  for (int j = 0; j < 4; ++j) {
    float inv = 1.f / l_run[j];
    int s = q0 + wave * 16 + fq * 4 + j;
#pragma unroll
    for (int nd = 0; nd < 8; ++nd) {
      int d = nd * 16 + fr;
      ctx[(((size_t)b * 2048 + s) * 16 + h) * 128 + d] = f2bf(acco[nd][j] * inv);
    }
  }
}

// ---------------------------------------------------------------------------
extern "C" void kernel_launch(void* const* d_in, const int* in_sizes, int n_in,
                              void* d_out, int out_size, void* d_ws, size_t ws_size,
                              hipStream_t stream)
{
  (void)in_sizes; (void)n_in; (void)out_size; (void)ws_size;
  const float* x       = (const float*)d_in[0];
  const float* w_qkv   = (const float*)d_in[1];
  const float* b_qkv   = (const float*)d_in[2];
  const float* w_dense = (const float*)d_in[3];
  const float* b_dense = (const float*)d_in[4];
  float* out = (float*)d_out;

  char* ws = (char*)d_ws;
  __hip_bfloat16* x_bf     = (__hip_bfloat16*)(ws);                  // 16MB
  __hip_bfloat16* wqkv_t   = (__hip_bfloat16*)(ws + 16777216);       // 24MB
  __hip_bfloat16* wdense_t = (__hip_bfloat16*)(ws + 41943040);       // 8MB
  __hip_bfloat16* qb       = (__hip_bfloat16*)(ws + 50331648);       // 16MB
  __hip_bfloat16* kb       = (__hip_bfloat16*)(ws + 67108864);       // 16MB
  __hip_bfloat16* vtb      = (__hip_bfloat16*)(ws + 83886080);       // 16MB
  __hip_bfloat16* ctx      = (__hip_bfloat16*)(ws + 100663296);      // 16MB

  prep_kernel<<<8192, 256, 0, stream>>>(x, x_bf, w_qkv, wqkv_t, w_dense, wdense_t);
  // QKV: grid (4096/128)*(6144/192) = 32*32 = 1024 = 2 tail-free rounds @2/CU
  gemm192_qkv<<<1024, 512, 0, stream>>>(x_bf, wqkv_t, b_qkv,
                                        qb, kb, vtb, 4096, 6144, 2048);
  attn_kernel<<<1024, 256, 0, stream>>>(qb, kb, vtb, ctx);
  // dense: grid (4096/128)*(2048/256) = 256
  gemm8p<<<256, 512, 0, stream>>>(ctx, wdense_t, b_dense, out,
                                  4096, 2048, 2048);
}

// Round 12
// 260.368 us; speedup vs baseline: 1.1279x; 1.0219x over previous
//
#include <hip/hip_runtime.h>
#include <hip/hip_bf16.h>
#include <stdint.h>

#define DEV __device__ __forceinline__

typedef __attribute__((ext_vector_type(8))) short short8;
typedef __attribute__((ext_vector_type(8))) __bf16 bf16x8;
typedef __attribute__((ext_vector_type(4))) float f32x4;

typedef const __attribute__((address_space(1))) uint32_t gu32;
typedef __attribute__((address_space(3))) uint32_t lu32;

DEV void gload16(const void* g, void* l) {
  __builtin_amdgcn_global_load_lds((gu32*)g, (lu32*)l, 16, 0, 0);
}

DEV f32x4 mfma16(bf16x8 a, bf16x8 b, f32x4 c) {
  return __builtin_amdgcn_mfma_f32_16x16x32_bf16(a, b, c, 0, 0, 0);
}

DEV __hip_bfloat16 f2bf(float x) { return __float2bfloat16(x); }
DEV bf16x8 as_bf(short8 v) { union { short8 s; bf16x8 b; } u; u.s = v; return u.b; }

// ---------------------------------------------------------------------------
// Merged prepro: [0,4096) cvt x; [4096,7168) transpose w_qkv; rest w_dense.
// ---------------------------------------------------------------------------
__global__ __launch_bounds__(256)
void prep_kernel(const float* __restrict__ x, __hip_bfloat16* __restrict__ x_bf,
                 const float* __restrict__ w_qkv, __hip_bfloat16* __restrict__ wqkv_t,
                 const float* __restrict__ w_dense, __hip_bfloat16* __restrict__ wdense_t)
{
  __shared__ __hip_bfloat16 tile[64][72];
  const int tid = threadIdx.x;
  const int blk = blockIdx.x;

  if (blk < 4096) {
    int i = (blk * 256 + tid) * 8;
    f32x4 a = *(const f32x4*)&x[i];
    f32x4 b = *(const f32x4*)&x[i + 4];
    short8 o;
#pragma unroll
    for (int j = 0; j < 4; ++j) {
      o[j]     = __bfloat16_as_short(f2bf(a[j]));
      o[j + 4] = __bfloat16_as_short(f2bf(b[j]));
    }
    *(short8*)&x_bf[i] = o;
    return;
  }

  const float* src; __hip_bfloat16* dst; int K, N, bx, by;
  if (blk < 4096 + 3072) {
    int bb = blk - 4096; src = w_qkv; dst = wqkv_t; K = 2048; N = 6144;
    bx = bb % 96; by = bb / 96;
  } else {
    int bb = blk - 7168; src = w_dense; dst = wdense_t; K = 2048; N = 2048;
    bx = bb % 32; by = bb / 32;
  }
  const int k0 = by * 64, n0 = bx * 64;
  const int r = tid >> 3, c8 = tid & 7;
#pragma unroll
  for (int i = 0; i < 2; ++i) {
    int k = r + i * 32;
    f32x4 a = *(const f32x4*)&src[(size_t)(k0 + k) * N + n0 + c8 * 8];
    f32x4 b = *(const f32x4*)&src[(size_t)(k0 + k) * N + n0 + c8 * 8 + 4];
#pragma unroll
    for (int j = 0; j < 4; ++j) {
      tile[k][c8 * 8 + j]     = f2bf(a[j]);
      tile[k][c8 * 8 + 4 + j] = f2bf(b[j]);
    }
  }
  __syncthreads();
#pragma unroll
  for (int i = 0; i < 2; ++i) {
    int n = r + i * 32;
    short8 v;
#pragma unroll
    for (int j = 0; j < 8; ++j) v[j] = *(const short*)&tile[c8 * 8 + j][n];
    *(short8*)&dst[(size_t)(n0 + n) * K + k0 + c8 * 8] = v;
  }
}

// ---------------------------------------------------------------------------
// QKV GEMM v2: BM=128, BN=192, BK=64; 256 threads = 4 waves (2M x 2N),
// per-wave 64x96. Dup factor (A=2, B=2) -> 38.4 FLOP per LDS byte (was 27.4
// at 8 waves 2x4). LDS 80KB full dbuf -> 2 blocks/CU. Grid 1024 = 2
// tail-free rounds. r11 race-free gate structure, counts rescaled for 256
// threads (A unit = 4 loads/thread, B unit = 6):
//  p1: rd buf0.B(kk0+kk1)+A kk0; stage A(T+1)->buf1.A[4]; bar; 24 MFMA; bar
//  p2: rd buf0.A kk1; stage B(T+2)->buf0.B[6]; vmcnt(6); bar; MFMA; bar
//  p3: rd buf1.B(both)+A kk0;    stage A(T+2)->buf0.A[4]; bar; MFMA; bar
//  p4: rd buf1.A kk1; stage B(T+3)->buf1.B[6]; vmcnt(6); bar; MFMA; bar
// Invariant entering p1: outstanding = B(odd)[6]. Gates leave 6 in flight.
// ---------------------------------------------------------------------------
__global__ __launch_bounds__(256, 2)
void gemm192_qkv(const __hip_bfloat16* __restrict__ A,
                 const __hip_bfloat16* __restrict__ Bt,
                 const float* __restrict__ bias,
                 __hip_bfloat16* __restrict__ qb,
                 __hip_bfloat16* __restrict__ kb,
                 __hip_bfloat16* __restrict__ vtb,
                 int M, int N, int K)
{
  __shared__ __hip_bfloat16 As[2][128 * 64];   // 32KB
  __shared__ __hip_bfloat16 Bs[2][192 * 64];   // 48KB

  const int tid = threadIdx.x, lane = tid & 63, wave = tid >> 6;
  const int wm = wave >> 1, wn = wave & 1;

  // XCD partition: 4 consecutive N-cols per XCD
  const int lin = blockIdx.x;
  const int xcd = lin & 7, t2 = lin >> 3;
  const int bx = xcd * 4 + (t2 & 3);
  const int by = t2 >> 2;
  const int m0 = by * 128, n0 = bx * 192;

  const int fr = lane & 15, fq = lane >> 4;
  const int lrow = lane >> 3, lslot = lane & 7;

  auto stageA = [&](int kc, char* dst) {       // 4 loads: 128 rows (32/call)
#pragma unroll
    for (int r = 0; r < 4; ++r) {
      int rbase = r * 32 + wave * 8;
      int rr = rbase + lrow;
      int col = (lslot ^ (rr & 7)) << 3;
      gload16(&A[(size_t)(m0 + rr) * K + kc + col], dst + rbase * 128);
    }
  };
  auto stageB = [&](int kc, char* dst) {       // 6 loads: 192 rows
#pragma unroll
    for (int r = 0; r < 6; ++r) {
      int rbase = r * 32 + wave * 8;
      int rr = rbase + lrow;
      int col = (lslot ^ (rr & 7)) << 3;
      gload16(&Bt[(size_t)(n0 + rr) * K + kc + col], dst + rbase * 128);
    }
  };

  char* A0t = (char*)&As[0][0];  char* A1t = (char*)&As[1][0];
  char* B0t = (char*)&Bs[0][0];  char* B1t = (char*)&Bs[1][0];

  auto rdA = [&](const char* base, int mi, int kk) {   // mi 0..3
    int row = wm * 64 + mi * 16 + fr;
    int cb = (kk * 64 + fq * 16) ^ ((row & 7) << 4);
    return as_bf(*(const short8*)(base + row * 128 + cb));
  };
  auto rdB = [&](const char* base, int ni, int kk) {   // ni 0..5
    int row = wn * 96 + ni * 16 + fr;
    int cb = (kk * 64 + fq * 16) ^ ((row & 7) << 4);
    return as_bf(*(const short8*)(base + row * 128 + cb));
  };

  f32x4 acc[4][6] = {};
  const int nIt = K / 128;      // 16

  bf16x8 bk0[6], bk1[6], af[4];
  auto CLUST = [&](bf16x8* bv) {
    __builtin_amdgcn_s_setprio(1);
#pragma unroll
    for (int mi = 0; mi < 4; ++mi)
#pragma unroll
      for (int ni = 0; ni < 6; ++ni)
        acc[mi][ni] = mfma16(af[mi], bv[ni], acc[mi][ni]);
    __builtin_amdgcn_s_setprio(0);
  };

  // prologue: B(0),A(0)->buf0, B(1)->buf1.B; gate tile0; barrier.
  stageB(0, B0t); stageA(0, A0t); stageB(64, B1t);
  asm volatile("s_waitcnt vmcnt(6)" ::: "memory");   // B(0),A(0) landed
  __builtin_amdgcn_s_barrier();
  // invariant: outstanding = B(1)[6]

  for (int j = 0; j < nIt; ++j) {
    const int T = 2 * j;
    const bool pre = (j + 1 < nIt);
    const int kc1 = (T + 1) * 64, kc2 = (T + 2) * 64, kc3 = (T + 3) * 64;

    // ---- p1: read buf0.B both kk + A kk0; stage A(T+1)->buf1.A ----
#pragma unroll
    for (int ni = 0; ni < 6; ++ni) { bk0[ni] = rdB(B0t, ni, 0); bk1[ni] = rdB(B0t, ni, 1); }
#pragma unroll
    for (int mi = 0; mi < 4; ++mi) af[mi] = rdA(A0t, mi, 0);
    stageA(kc1, A1t);                              // outstanding 6+4=10
    __builtin_amdgcn_s_barrier();
    CLUST(bk0);
    __builtin_amdgcn_s_barrier();

    // ---- p2: read buf0.A kk1; stage B(T+2)->buf0.B; gate(T+1) ----
#pragma unroll
    for (int mi = 0; mi < 4; ++mi) af[mi] = rdA(A0t, mi, 1);
    if (pre) {
      stageB(kc2, B0t);                            // outstanding 16
      asm volatile("s_waitcnt vmcnt(6)" ::: "memory");  // B(T+1),A(T+1) landed
    } else {
      asm volatile("s_waitcnt vmcnt(0)" ::: "memory");
    }
    __builtin_amdgcn_s_barrier();
    CLUST(bk1);
    __builtin_amdgcn_s_barrier();

    // ---- p3: read buf1.B both kk + A kk0; stage A(T+2)->buf0.A ----
#pragma unroll
    for (int ni = 0; ni < 6; ++ni) { bk0[ni] = rdB(B1t, ni, 0); bk1[ni] = rdB(B1t, ni, 1); }
#pragma unroll
    for (int mi = 0; mi < 4; ++mi) af[mi] = rdA(A1t, mi, 0);
    if (pre) stageA(kc2, A0t);                     // outstanding 10
    __builtin_amdgcn_s_barrier();
    CLUST(bk0);
    __builtin_amdgcn_s_barrier();

    // ---- p4: read buf1.A kk1; stage B(T+3)->buf1.B; gate(T+2) ----
#pragma unroll
    for (int mi = 0; mi < 4; ++mi) af[mi] = rdA(A1t, mi, 1);
    if (pre) {
      stageB(kc3, B1t);                            // outstanding 16
      asm volatile("s_waitcnt vmcnt(6)" ::: "memory");  // B(T+2),A(T+2) landed
    }
    __builtin_amdgcn_s_barrier();
    CLUST(bk1);
    __builtin_amdgcn_s_barrier();
  }

  // epilogue: scatter q/k/v^T. Per-ni (head, qkv-type) uniform (16 | 128).
#pragma unroll
  for (int ni = 0; ni < 6; ++ni) {
    const int nb = n0 + wn * 96 + ni * 16;
    const int h = nb / 384;
    const int rb = nb - h * 384;
    const int t3 = rb >> 7;
    const int dloc = (rb & 127) + fr;
    const float bv = bias[nb + fr];
#pragma unroll
    for (int mi = 0; mi < 4; ++mi) {
      const int mbase = m0 + wm * 64 + mi * 16 + fq * 4;
#pragma unroll
      for (int jj = 0; jj < 4; ++jj) {
        const int m = mbase + jj;
        const int b = m >> 11, s = m & 2047;
        const int bh = b * 16 + h;
        const float v = acc[mi][ni][jj] + bv;
        if (t3 == 0)      qb[((size_t)bh * 2048 + s) * 128 + dloc] = f2bf(v);
        else if (t3 == 1) kb[((size_t)bh * 2048 + s) * 128 + dloc] = f2bf(v);
        else              vtb[((size_t)bh * 128 + dloc) * 2048 + s] = f2bf(v);
      }
    }
  }
}

// ---------------------------------------------------------------------------
// Deep-pipelined 128x256 GEMM (r7 structure) — dense projection. Grid 256.
// ---------------------------------------------------------------------------
__global__ __launch_bounds__(512, 2)
void gemm8p(const __hip_bfloat16* __restrict__ A,
            const __hip_bfloat16* __restrict__ Bt,
            const float* __restrict__ bias,
            float* __restrict__ C,
            int M, int N, int K)
{
  __shared__ __hip_bfloat16 As[2][128 * 64];
  __shared__ __hip_bfloat16 Bs[2][256 * 64];

  const int tid = threadIdx.x, lane = tid & 63, wave = tid >> 6;
  const int wm = wave >> 2, wn = wave & 3;

  const int gx = N >> 8;
  const int cpx = gx >> 3;
  const int lin = blockIdx.x;
  const int xcd = lin & 7, t2 = lin >> 3;
  const int bx = xcd * cpx + (t2 % cpx);
  const int by = t2 / cpx;
  const int m0 = by * 128, n0 = bx * 256;

  const int fr = lane & 15, fq = lane >> 4;
  const int lrow = lane >> 3, lslot = lane & 7;

  auto stage = [&](const __hip_bfloat16* src, int srow0, int kc, char* dstTile) {
#pragma unroll
    for (int r = 0; r < 2; ++r) {
      int rbase = r * 64 + wave * 8;
      int rr = rbase + lrow;
      int col = (lslot ^ (rr & 7)) << 3;
      gload16(&src[(size_t)(srow0 + rr) * K + kc + col], dstTile + rbase * 128);
    }
  };

  char* A0 = (char*)&As[0][0];  char* A1 = (char*)&As[1][0];
  char* B0 = (char*)&Bs[0][0];  char* B1 = (char*)&Bs[1][0];

  auto rdA = [&](const char* base, int mi, int kk) {
    int row = wm * 64 + mi * 16 + fr;
    int cb = (kk * 64 + fq * 16) ^ ((row & 7) << 4);
    return as_bf(*(const short8*)(base + row * 128 + cb));
  };
  auto rdB = [&](const char* base, int ni, int kk) {
    int row = wn * 64 + ni * 16 + fr;
    int cb = (kk * 64 + fq * 16) ^ ((row & 7) << 4);
    return as_bf(*(const short8*)(base + row * 128 + cb));
  };

  f32x4 acc[4][4] = {};
  const int kt = K / 64;
  const int nIt = kt / 2;

  stage(Bt, n0,       0, B0); stage(Bt, n0 + 128,  0, B0 + 128 * 128);
  stage(A,  m0,       0, A0);
  stage(Bt, n0,      64, B1); stage(Bt, n0 + 128, 64, B1 + 128 * 128);
  stage(A,  m0,      64, A1);
  asm volatile("s_waitcnt vmcnt(6)" ::: "memory");
  __builtin_amdgcn_s_barrier();

  for (int j = 0; j < nIt; ++j) {
    const int T = 2 * j;
    const bool last = (j == nIt - 1);
    const int kc2 = (T + 2) * 64, kc3 = (T + 3) * 64;
    bf16x8 bfr[4][2], afr[2][2];

#pragma unroll
    for (int ni = 0; ni < 4; ++ni) { bfr[ni][0] = rdB(B0, ni, 0); bfr[ni][1] = rdB(B0, ni, 1); }
#pragma unroll
    for (int mi = 0; mi < 2; ++mi) { afr[mi][0] = rdA(A0, mi, 0); afr[mi][1] = rdA(A0, mi, 1); }
    __builtin_amdgcn_s_barrier();
    __builtin_amdgcn_s_setprio(1);
#pragma unroll
    for (int kk = 0; kk < 2; ++kk)
#pragma unroll
      for (int mi = 0; mi < 2; ++mi)
#pragma unroll
        for (int ni = 0; ni < 4; ++ni)
          acc[mi][ni] = mfma16(afr[mi][kk], bfr[ni][kk], acc[mi][ni]);
    __builtin_amdgcn_s_setprio(0);
    __builtin_amdgcn_s_barrier();

#pragma unroll
    for (int mi = 0; mi < 2; ++mi) { afr[mi][0] = rdA(A0, mi + 2, 0); afr[mi][1] = rdA(A0, mi + 2, 1); }
    if (!last) {
      stage(Bt, n0, kc2, B0);
      asm volatile("s_waitcnt vmcnt(2)" ::: "memory");
    } else {
      asm volatile("s_waitcnt vmcnt(0)" ::: "memory");
    }
    __builtin_amdgcn_s_barrier();
    __builtin_amdgcn_s_setprio(1);
#pragma unroll
    for (int kk = 0; kk < 2; ++kk)
#pragma unroll
      for (int mi = 0; mi < 2; ++mi)
#pragma unroll
        for (int ni = 0; ni < 4; ++ni)
          acc[mi + 2][ni] = mfma16(afr[mi][kk], bfr[ni][kk], acc[mi + 2][ni]);
    __builtin_amdgcn_s_setprio(0);
    __builtin_amdgcn_s_barrier();

#pragma unroll
    for (int ni = 0; ni < 4; ++ni) { bfr[ni][0] = rdB(B1, ni, 0); bfr[ni][1] = rdB(B1, ni, 1); }
#pragma unroll
    for (int mi = 0; mi < 2; ++mi) { afr[mi][0] = rdA(A1, mi, 0); afr[mi][1] = rdA(A1, mi, 1); }
    if (!last) {
      stage(Bt, n0 + 128, kc2, B0 + 128 * 128);
      stage(A,  m0,       kc2, A0);
    }
    __builtin_amdgcn_s_barrier();
    __builtin_amdgcn_s_setprio(1);
#pragma unroll
    for (int kk = 0; kk < 2; ++kk)
#pragma unroll
      for (int mi = 0; mi < 2; ++mi)
#pragma unroll
        for (int ni = 0; ni < 4; ++ni)
          acc[mi][ni] = mfma16(afr[mi][kk], bfr[ni][kk], acc[mi][ni]);
    __builtin_amdgcn_s_setprio(0);
    __builtin_amdgcn_s_barrier();

#pragma unroll
    for (int mi = 0; mi < 2; ++mi) { afr[mi][0] = rdA(A1, mi + 2, 0); afr[mi][1] = rdA(A1, mi + 2, 1); }
    if (!last) {
      stage(Bt, n0,       kc3, B1);
      stage(Bt, n0 + 128, kc3, B1 + 128 * 128);
      asm volatile("s_waitcnt vmcnt(4)" ::: "memory");
    } else {
      asm volatile("s_waitcnt vmcnt(0)" ::: "memory");
    }
    __builtin_amdgcn_s_barrier();
    __builtin_amdgcn_s_setprio(1);
#pragma unroll
    for (int kk = 0; kk < 2; ++kk)
#pragma unroll
      for (int mi = 0; mi < 2; ++mi)
#pragma unroll
        for (int ni = 0; ni < 4; ++ni)
          acc[mi + 2][ni] = mfma16(afr[mi][kk], bfr[ni][kk], acc[mi + 2][ni]);
    __builtin_amdgcn_s_setprio(0);
    if (!last) stage(A, m0, kc3, A1);
    __builtin_amdgcn_s_barrier();
  }

#pragma unroll
  for (int ni = 0; ni < 4; ++ni) {
    int n = n0 + wn * 64 + ni * 16 + fr;
    float bv = bias[n];
#pragma unroll
    for (int mi = 0; mi < 4; ++mi) {
      int mbase = m0 + wm * 64 + mi * 16 + fq * 4;
#pragma unroll
      for (int jj = 0; jj < 4; ++jj)
        C[(size_t)(mbase + jj) * N + n] = acc[mi][ni][jj] + bv;
    }
  }
}

// ---------------------------------------------------------------------------
// Causal flash attention (QBLK=64, heavy-first, double-buffered, setprio).
// ---------------------------------------------------------------------------
__global__ __launch_bounds__(256)
void attn_kernel(const __hip_bfloat16* __restrict__ qb,
                 const __hip_bfloat16* __restrict__ kb,
                 const __hip_bfloat16* __restrict__ vtb,
                 __hip_bfloat16* __restrict__ ctx)
{
  __shared__ __hip_bfloat16 Ks[2][64 * 128];
  __shared__ __hip_bfloat16 Vts[2][128 * 64];
  __shared__ __hip_bfloat16 Ps[4][16 * 64];

  const int tid = threadIdx.x, lane = tid & 63, wave = tid >> 6;
  const int fr = lane & 15, fq = lane >> 4;
  const int blk = blockIdx.x;
  const int qi = 31 - (blk >> 5);
  const int bh = blk & 31;
  const int q0 = qi * 64;

  bf16x8 qf[4];
  const int qrow = q0 + wave * 16 + fr;
#pragma unroll
  for (int kf = 0; kf < 4; ++kf)
    qf[kf] = as_bf(*(const short8*)&qb[((size_t)bh * 2048 + qrow) * 128 + kf * 32 + fq * 8]);

  f32x4 acco[8] = {};
  float m_run[4] = {-1e30f, -1e30f, -1e30f, -1e30f};
  float l_run[4] = {0.f, 0.f, 0.f, 0.f};

  char* Pb = (char*)&Ps[wave][0];
  const int nt = qi + 1;

  auto STAGE = [&](int t, int buf) {
    const int k0t = t * 64;
#pragma unroll
    for (int i = 0; i < 4; ++i) {
      int c = wave * 4 + i;
      int kv = c * 4 + fq;
      int cb = (fr * 16) ^ ((kv & 7) << 4);
      gload16(&kb[((size_t)bh * 2048 + k0t + kv) * 128 + (cb >> 1)], &Ks[buf][c * 512]);
    }
#pragma unroll
    for (int i = 0; i < 4; ++i) {
      int c = wave * 4 + i;
      int d = c * 8 + (lane >> 3);
      int cb = ((lane & 7) * 16) ^ ((d & 7) << 4);
      gload16(&vtb[((size_t)bh * 128 + d) * 2048 + k0t + (cb >> 1)], &Vts[buf][c * 512]);
    }
  };

  STAGE(0, 0);
  __syncthreads();

  int cur = 0;
  for (int t = 0; t < nt; ++t) {
    if (t + 1 < nt) STAGE(t + 1, cur ^ 1);
    const char* Kb = (const char*)&Ks[cur][0];
    const char* Vb = (const char*)&Vts[cur][0];
    const int k0 = t * 64;

    f32x4 sacc[4] = {};
    __builtin_amdgcn_s_setprio(1);
#pragma unroll
    for (int kf = 0; kf < 4; ++kf) {
#pragma unroll
      for (int ni = 0; ni < 4; ++ni) {
        int kv = ni * 16 + fr;
        int cb = (kf * 64 + fq * 16) ^ ((kv & 7) << 4);
        bf16x8 kfr = as_bf(*(const short8*)(Kb + kv * 256 + cb));
        sacc[ni] = mfma16(qf[kf], kfr, sacc[ni]);
      }
    }
    __builtin_amdgcn_s_setprio(0);

    const float scale = 0.088388347648318447f;
    float sv[4][4];
    float rmax[4] = {-1e30f, -1e30f, -1e30f, -1e30f};
#pragma unroll
    for (int ni = 0; ni < 4; ++ni) {
      int kv_g = k0 + ni * 16 + fr;
#pragma unroll
      for (int j = 0; j < 4; ++j) {
        int q_g = q0 + wave * 16 + fq * 4 + j;
        float s = sacc[ni][j] * scale;
        if (kv_g > q_g) s = -10000.f;
        sv[ni][j] = s;
        rmax[j] = fmaxf(rmax[j], s);
      }
    }
#pragma unroll
    for (int off = 1; off < 16; off <<= 1)
#pragma unroll
      for (int j = 0; j < 4; ++j)
        rmax[j] = fmaxf(rmax[j], __shfl_xor(rmax[j], off));

    float alpha[4], rsum[4];
#pragma unroll
    for (int j = 0; j < 4; ++j) {
      float mn = fmaxf(m_run[j], rmax[j]);
      alpha[j] = __expf(m_run[j] - mn);
      m_run[j] = mn;
      rsum[j] = 0.f;
    }
#pragma unroll
    for (int ni = 0; ni < 4; ++ni) {
#pragma unroll
      for (int j = 0; j < 4; ++j) {
        float p = __expf(sv[ni][j] - m_run[j]);
        rsum[j] += p;
        int prow = fq * 4 + j;
        int cbw = ((ni * 16 + fr) * 2) ^ ((prow & 7) << 4);
        *(__hip_bfloat16*)(Pb + prow * 128 + cbw) = f2bf(p);
      }
    }
#pragma unroll
    for (int off = 1; off < 16; off <<= 1)
#pragma unroll
      for (int j = 0; j < 4; ++j)
        rsum[j] += __shfl_xor(rsum[j], off);
#pragma unroll
    for (int j = 0; j < 4; ++j)
      l_run[j] = l_run[j] * alpha[j] + rsum[j];

#pragma unroll
    for (int nd = 0; nd < 8; ++nd)
#pragma unroll
      for (int j = 0; j < 4; ++j)
        acco[nd][j] *= alpha[j];

    asm volatile("s_waitcnt lgkmcnt(0)" ::: "memory");
    __builtin_amdgcn_sched_barrier(0);

    __builtin_amdgcn_s_setprio(1);
#pragma unroll
    for (int kf2 = 0; kf2 < 2; ++kf2) {
      int cbp = (kf2 * 64 + fq * 16) ^ ((fr & 7) << 4);
      bf16x8 pa = as_bf(*(const short8*)(Pb + fr * 128 + cbp));
#pragma unroll
      for (int nd = 0; nd < 8; ++nd) {
        int d = nd * 16 + fr;
        int cbv = (kf2 * 64 + fq * 16) ^ ((d & 7) << 4);
        bf16x8 vfr = as_bf(*(const short8*)(Vb + d * 128 + cbv));
        acco[nd] = mfma16(pa, vfr, acco[nd]);
      }
    }
    __builtin_amdgcn_s_setprio(0);
    __syncthreads();
    cur ^= 1;
  }

  const int b = bh >> 4, h = bh & 15;
#pragma unroll
  for (int j = 0; j < 4; ++j) {
    float inv = 1.f / l_run[j];
    int s = q0 + wave * 16 + fq * 4 + j;
#pragma unroll
    for (int nd = 0; nd < 8; ++nd) {
      int d = nd * 16 + fr;
      ctx[(((size_t)b * 2048 + s) * 16 + h) * 128 + d] = f2bf(acco[nd][j] * inv);
    }
  }
}

// ---------------------------------------------------------------------------
extern "C" void kernel_launch(void* const* d_in, const int* in_sizes, int n_in,
                              void* d_out, int out_size, void* d_ws, size_t ws_size,
                              hipStream_t stream)
{
  (void)in_sizes; (void)n_in; (void)out_size; (void)ws_size;
  const float* x       = (const float*)d_in[0];
  const float* w_qkv   = (const float*)d_in[1];
  const float* b_qkv   = (const float*)d_in[2];
  const float* w_dense = (const float*)d_in[3];
  const float* b_dense = (const float*)d_in[4];
  float* out = (float*)d_out;

  char* ws = (char*)d_ws;
  __hip_bfloat16* x_bf     = (__hip_bfloat16*)(ws);                  // 16MB
  __hip_bfloat16* wqkv_t   = (__hip_bfloat16*)(ws + 16777216);       // 24MB
  __hip_bfloat16* wdense_t = (__hip_bfloat16*)(ws + 41943040);       // 8MB
  __hip_bfloat16* qb       = (__hip_bfloat16*)(ws + 50331648);       // 16MB
  __hip_bfloat16* kb       = (__hip_bfloat16*)(ws + 67108864);       // 16MB
  __hip_bfloat16* vtb      = (__hip_bfloat16*)(ws + 83886080);       // 16MB
  __hip_bfloat16* ctx      = (__hip_bfloat16*)(ws + 100663296);      // 16MB

  prep_kernel<<<8192, 256, 0, stream>>>(x, x_bf, w_qkv, wqkv_t, w_dense, wdense_t);
  // QKV: grid (4096/128)*(6144/192) = 32*32 = 1024 = 2 tail-free rounds @2/CU
  gemm192_qkv<<<1024, 256, 0, stream>>>(x_bf, wqkv_t, b_qkv,
                                        qb, kb, vtb, 4096, 6144, 2048);
  attn_kernel<<<1024, 256, 0, stream>>>(qb, kb, vtb, ctx);
  // dense: grid (4096/128)*(2048/256) = 256
  gemm8p<<<256, 512, 0, stream>>>(ctx, wdense_t, b_dense, out,
                                  4096, 2048, 2048);
}

// Round 13
// 256.213 us; speedup vs baseline: 1.1462x; 1.0162x over previous
//
#include <hip/hip_runtime.h>
#include <hip/hip_bf16.h>
#include <stdint.h>

#define DEV __device__ __forceinline__

typedef __attribute__((ext_vector_type(8))) short short8;
typedef __attribute__((ext_vector_type(8))) __bf16 bf16x8;
typedef __attribute__((ext_vector_type(4))) float f32x4;

typedef const __attribute__((address_space(1))) uint32_t gu32;
typedef __attribute__((address_space(3))) uint32_t lu32;

DEV void gload16(const void* g, void* l) {
  __builtin_amdgcn_global_load_lds((gu32*)g, (lu32*)l, 16, 0, 0);
}

DEV f32x4 mfma16(bf16x8 a, bf16x8 b, f32x4 c) {
  return __builtin_amdgcn_mfma_f32_16x16x32_bf16(a, b, c, 0, 0, 0);
}

DEV __hip_bfloat16 f2bf(float x) { return __float2bfloat16(x); }
DEV bf16x8 as_bf(short8 v) { union { short8 s; bf16x8 b; } u; u.s = v; return u.b; }

// ---------------------------------------------------------------------------
// Merged prepro: [0,4096) cvt x; [4096,7168) transpose w_qkv; rest w_dense.
// ---------------------------------------------------------------------------
__global__ __launch_bounds__(256)
void prep_kernel(const float* __restrict__ x, __hip_bfloat16* __restrict__ x_bf,
                 const float* __restrict__ w_qkv, __hip_bfloat16* __restrict__ wqkv_t,
                 const float* __restrict__ w_dense, __hip_bfloat16* __restrict__ wdense_t)
{
  __shared__ __hip_bfloat16 tile[64][72];
  const int tid = threadIdx.x;
  const int blk = blockIdx.x;

  if (blk < 4096) {
    int i = (blk * 256 + tid) * 8;
    f32x4 a = *(const f32x4*)&x[i];
    f32x4 b = *(const f32x4*)&x[i + 4];
    short8 o;
#pragma unroll
    for (int j = 0; j < 4; ++j) {
      o[j]     = __bfloat16_as_short(f2bf(a[j]));
      o[j + 4] = __bfloat16_as_short(f2bf(b[j]));
    }
    *(short8*)&x_bf[i] = o;
    return;
  }

  const float* src; __hip_bfloat16* dst; int K, N, bx, by;
  if (blk < 4096 + 3072) {
    int bb = blk - 4096; src = w_qkv; dst = wqkv_t; K = 2048; N = 6144;
    bx = bb % 96; by = bb / 96;
  } else {
    int bb = blk - 7168; src = w_dense; dst = wdense_t; K = 2048; N = 2048;
    bx = bb % 32; by = bb / 32;
  }
  const int k0 = by * 64, n0 = bx * 64;
  const int r = tid >> 3, c8 = tid & 7;
#pragma unroll
  for (int i = 0; i < 2; ++i) {
    int k = r + i * 32;
    f32x4 a = *(const f32x4*)&src[(size_t)(k0 + k) * N + n0 + c8 * 8];
    f32x4 b = *(const f32x4*)&src[(size_t)(k0 + k) * N + n0 + c8 * 8 + 4];
#pragma unroll
    for (int j = 0; j < 4; ++j) {
      tile[k][c8 * 8 + j]     = f2bf(a[j]);
      tile[k][c8 * 8 + 4 + j] = f2bf(b[j]);
    }
  }
  __syncthreads();
#pragma unroll
  for (int i = 0; i < 2; ++i) {
    int n = r + i * 32;
    short8 v;
#pragma unroll
    for (int j = 0; j < 8; ++j) v[j] = *(const short*)&tile[c8 * 8 + j][n];
    *(short8*)&dst[(size_t)(n0 + n) * K + k0 + c8 * 8] = v;
  }
}

// ---------------------------------------------------------------------------
// QKV GEMM (r12, unchanged): BM=128, BN=192, BK=64; 256 thr = 4 waves (2x2),
// per-wave 64x96; LDS 80KB dbuf -> 2 blocks/CU; grid 1024 = 2 exact rounds.
// Race-free gates: every vmcnt immediately precedes a barrier; protected
// reads are in the NEXT phase. Gates leave 6 loads in flight (never drain).
// ---------------------------------------------------------------------------
__global__ __launch_bounds__(256, 2)
void gemm192_qkv(const __hip_bfloat16* __restrict__ A,
                 const __hip_bfloat16* __restrict__ Bt,
                 const float* __restrict__ bias,
                 __hip_bfloat16* __restrict__ qb,
                 __hip_bfloat16* __restrict__ kb,
                 __hip_bfloat16* __restrict__ vtb,
                 int M, int N, int K)
{
  __shared__ __hip_bfloat16 As[2][128 * 64];   // 32KB
  __shared__ __hip_bfloat16 Bs[2][192 * 64];   // 48KB

  const int tid = threadIdx.x, lane = tid & 63, wave = tid >> 6;
  const int wm = wave >> 1, wn = wave & 1;

  const int lin = blockIdx.x;
  const int xcd = lin & 7, t2 = lin >> 3;
  const int bx = xcd * 4 + (t2 & 3);
  const int by = t2 >> 2;
  const int m0 = by * 128, n0 = bx * 192;

  const int fr = lane & 15, fq = lane >> 4;
  const int lrow = lane >> 3, lslot = lane & 7;

  auto stageA = [&](int kc, char* dst) {       // 4 loads: 128 rows
#pragma unroll
    for (int r = 0; r < 4; ++r) {
      int rbase = r * 32 + wave * 8;
      int rr = rbase + lrow;
      int col = (lslot ^ (rr & 7)) << 3;
      gload16(&A[(size_t)(m0 + rr) * K + kc + col], dst + rbase * 128);
    }
  };
  auto stageB = [&](int kc, char* dst) {       // 6 loads: 192 rows
#pragma unroll
    for (int r = 0; r < 6; ++r) {
      int rbase = r * 32 + wave * 8;
      int rr = rbase + lrow;
      int col = (lslot ^ (rr & 7)) << 3;
      gload16(&Bt[(size_t)(n0 + rr) * K + kc + col], dst + rbase * 128);
    }
  };

  char* A0t = (char*)&As[0][0];  char* A1t = (char*)&As[1][0];
  char* B0t = (char*)&Bs[0][0];  char* B1t = (char*)&Bs[1][0];

  auto rdA = [&](const char* base, int mi, int kk) {
    int row = wm * 64 + mi * 16 + fr;
    int cb = (kk * 64 + fq * 16) ^ ((row & 7) << 4);
    return as_bf(*(const short8*)(base + row * 128 + cb));
  };
  auto rdB = [&](const char* base, int ni, int kk) {
    int row = wn * 96 + ni * 16 + fr;
    int cb = (kk * 64 + fq * 16) ^ ((row & 7) << 4);
    return as_bf(*(const short8*)(base + row * 128 + cb));
  };

  f32x4 acc[4][6] = {};
  const int nIt = K / 128;

  bf16x8 bk0[6], bk1[6], af[4];
  auto CLUST = [&](bf16x8* bv) {
    __builtin_amdgcn_s_setprio(1);
#pragma unroll
    for (int mi = 0; mi < 4; ++mi)
#pragma unroll
      for (int ni = 0; ni < 6; ++ni)
        acc[mi][ni] = mfma16(af[mi], bv[ni], acc[mi][ni]);
    __builtin_amdgcn_s_setprio(0);
  };

  stageB(0, B0t); stageA(0, A0t); stageB(64, B1t);
  asm volatile("s_waitcnt vmcnt(6)" ::: "memory");
  __builtin_amdgcn_s_barrier();

  for (int j = 0; j < nIt; ++j) {
    const int T = 2 * j;
    const bool pre = (j + 1 < nIt);
    const int kc1 = (T + 1) * 64, kc2 = (T + 2) * 64, kc3 = (T + 3) * 64;

#pragma unroll
    for (int ni = 0; ni < 6; ++ni) { bk0[ni] = rdB(B0t, ni, 0); bk1[ni] = rdB(B0t, ni, 1); }
#pragma unroll
    for (int mi = 0; mi < 4; ++mi) af[mi] = rdA(A0t, mi, 0);
    stageA(kc1, A1t);
    __builtin_amdgcn_s_barrier();
    CLUST(bk0);
    __builtin_amdgcn_s_barrier();

#pragma unroll
    for (int mi = 0; mi < 4; ++mi) af[mi] = rdA(A0t, mi, 1);
    if (pre) {
      stageB(kc2, B0t);
      asm volatile("s_waitcnt vmcnt(6)" ::: "memory");
    } else {
      asm volatile("s_waitcnt vmcnt(0)" ::: "memory");
    }
    __builtin_amdgcn_s_barrier();
    CLUST(bk1);
    __builtin_amdgcn_s_barrier();

#pragma unroll
    for (int ni = 0; ni < 6; ++ni) { bk0[ni] = rdB(B1t, ni, 0); bk1[ni] = rdB(B1t, ni, 1); }
#pragma unroll
    for (int mi = 0; mi < 4; ++mi) af[mi] = rdA(A1t, mi, 0);
    if (pre) stageA(kc2, A0t);
    __builtin_amdgcn_s_barrier();
    CLUST(bk0);
    __builtin_amdgcn_s_barrier();

#pragma unroll
    for (int mi = 0; mi < 4; ++mi) af[mi] = rdA(A1t, mi, 1);
    if (pre) {
      stageB(kc3, B1t);
      asm volatile("s_waitcnt vmcnt(6)" ::: "memory");
    }
    __builtin_amdgcn_s_barrier();
    CLUST(bk1);
    __builtin_amdgcn_s_barrier();
  }

#pragma unroll
  for (int ni = 0; ni < 6; ++ni) {
    const int nb = n0 + wn * 96 + ni * 16;
    const int h = nb / 384;
    const int rb = nb - h * 384;
    const int t3 = rb >> 7;
    const int dloc = (rb & 127) + fr;
    const float bv = bias[nb + fr];
#pragma unroll
    for (int mi = 0; mi < 4; ++mi) {
      const int mbase = m0 + wm * 64 + mi * 16 + fq * 4;
#pragma unroll
      for (int jj = 0; jj < 4; ++jj) {
        const int m = mbase + jj;
        const int b = m >> 11, s = m & 2047;
        const int bh = b * 16 + h;
        const float v = acc[mi][ni][jj] + bv;
        if (t3 == 0)      qb[((size_t)bh * 2048 + s) * 128 + dloc] = f2bf(v);
        else if (t3 == 1) kb[((size_t)bh * 2048 + s) * 128 + dloc] = f2bf(v);
        else              vtb[((size_t)bh * 128 + dloc) * 2048 + s] = f2bf(v);
      }
    }
  }
}

// ---------------------------------------------------------------------------
// Dense GEMM: BM=BN=128, BK=64; 256 thr = 4 waves (2x2), per-wave 64x64.
// LDS 64KB dbuf -> 2 blocks/CU. Grid 512 = 2 exact rounds. Same race-free
// gate structure as gemm192 (A unit = 4 loads, B unit = 4; gates vmcnt(4)).
// ---------------------------------------------------------------------------
__global__ __launch_bounds__(256, 2)
void gemm128_dense(const __hip_bfloat16* __restrict__ A,
                   const __hip_bfloat16* __restrict__ Bt,
                   const float* __restrict__ bias,
                   float* __restrict__ C,
                   int M, int N, int K)
{
  __shared__ __hip_bfloat16 As[2][128 * 64];   // 32KB
  __shared__ __hip_bfloat16 Bs[2][128 * 64];   // 32KB

  const int tid = threadIdx.x, lane = tid & 63, wave = tid >> 6;
  const int wm = wave >> 1, wn = wave & 1;

  // XCD partition: 2 consecutive N-cols per XCD (gx = 16)
  const int lin = blockIdx.x;
  const int xcd = lin & 7, t2 = lin >> 3;      // t2 in [0,64)
  const int bx = xcd * 2 + (t2 & 1);           // [0,16)
  const int by = t2 >> 1;                      // [0,32)
  const int m0 = by * 128, n0 = bx * 128;

  const int fr = lane & 15, fq = lane >> 4;
  const int lrow = lane >> 3, lslot = lane & 7;

  auto stageT = [&](const __hip_bfloat16* src, int row0, int kc, char* dst) {
#pragma unroll
    for (int r = 0; r < 4; ++r) {
      int rbase = r * 32 + wave * 8;
      int rr = rbase + lrow;
      int col = (lslot ^ (rr & 7)) << 3;
      gload16(&src[(size_t)(row0 + rr) * K + kc + col], dst + rbase * 128);
    }
  };

  char* A0t = (char*)&As[0][0];  char* A1t = (char*)&As[1][0];
  char* B0t = (char*)&Bs[0][0];  char* B1t = (char*)&Bs[1][0];

  auto rdA = [&](const char* base, int mi, int kk) {
    int row = wm * 64 + mi * 16 + fr;
    int cb = (kk * 64 + fq * 16) ^ ((row & 7) << 4);
    return as_bf(*(const short8*)(base + row * 128 + cb));
  };
  auto rdB = [&](const char* base, int ni, int kk) {
    int row = wn * 64 + ni * 16 + fr;
    int cb = (kk * 64 + fq * 16) ^ ((row & 7) << 4);
    return as_bf(*(const short8*)(base + row * 128 + cb));
  };

  f32x4 acc[4][4] = {};
  const int nIt = K / 128;      // 16

  bf16x8 bk0[4], bk1[4], af[4];
  auto CLUST = [&](bf16x8* bv) {
    __builtin_amdgcn_s_setprio(1);
#pragma unroll
    for (int mi = 0; mi < 4; ++mi)
#pragma unroll
      for (int ni = 0; ni < 4; ++ni)
        acc[mi][ni] = mfma16(af[mi], bv[ni], acc[mi][ni]);
    __builtin_amdgcn_s_setprio(0);
  };

  // prologue: B(0),A(0)->buf0, B(1)->buf1.B; gate tile0; barrier.
  stageT(Bt, n0, 0, B0t); stageT(A, m0, 0, A0t); stageT(Bt, n0, 64, B1t);
  asm volatile("s_waitcnt vmcnt(4)" ::: "memory");   // B(0),A(0) landed
  __builtin_amdgcn_s_barrier();
  // invariant: outstanding = B(odd)[4]

  for (int j = 0; j < nIt; ++j) {
    const int T = 2 * j;
    const bool pre = (j + 1 < nIt);
    const int kc1 = (T + 1) * 64, kc2 = (T + 2) * 64, kc3 = (T + 3) * 64;

    // p1: read buf0.B both kk + A kk0; stage A(T+1)->buf1.A
#pragma unroll
    for (int ni = 0; ni < 4; ++ni) { bk0[ni] = rdB(B0t, ni, 0); bk1[ni] = rdB(B0t, ni, 1); }
#pragma unroll
    for (int mi = 0; mi < 4; ++mi) af[mi] = rdA(A0t, mi, 0);
    stageT(A, m0, kc1, A1t);
    __builtin_amdgcn_s_barrier();
    CLUST(bk0);
    __builtin_amdgcn_s_barrier();

    // p2: read buf0.A kk1; stage B(T+2)->buf0.B; gate(T+1)
#pragma unroll
    for (int mi = 0; mi < 4; ++mi) af[mi] = rdA(A0t, mi, 1);
    if (pre) {
      stageT(Bt, n0, kc2, B0t);
      asm volatile("s_waitcnt vmcnt(4)" ::: "memory");  // B(T+1),A(T+1) landed
    } else {
      asm volatile("s_waitcnt vmcnt(0)" ::: "memory");
    }
    __builtin_amdgcn_s_barrier();
    CLUST(bk1);
    __builtin_amdgcn_s_barrier();

    // p3: read buf1.B both kk + A kk0; stage A(T+2)->buf0.A
#pragma unroll
    for (int ni = 0; ni < 4; ++ni) { bk0[ni] = rdB(B1t, ni, 0); bk1[ni] = rdB(B1t, ni, 1); }
#pragma unroll
    for (int mi = 0; mi < 4; ++mi) af[mi] = rdA(A1t, mi, 0);
    if (pre) stageT(A, m0, kc2, A0t);
    __builtin_amdgcn_s_barrier();
    CLUST(bk0);
    __builtin_amdgcn_s_barrier();

    // p4: read buf1.A kk1; stage B(T+3)->buf1.B; gate(T+2)
#pragma unroll
    for (int mi = 0; mi < 4; ++mi) af[mi] = rdA(A1t, mi, 1);
    if (pre) {
      stageT(Bt, n0, kc3, B1t);
      asm volatile("s_waitcnt vmcnt(4)" ::: "memory");  // B(T+2),A(T+2) landed
    }
    __builtin_amdgcn_s_barrier();
    CLUST(bk1);
    __builtin_amdgcn_s_barrier();
  }

#pragma unroll
  for (int ni = 0; ni < 4; ++ni) {
    int n = n0 + wn * 64 + ni * 16 + fr;
    float bv = bias[n];
#pragma unroll
    for (int mi = 0; mi < 4; ++mi) {
      int mbase = m0 + wm * 64 + mi * 16 + fq * 4;
#pragma unroll
      for (int jj = 0; jj < 4; ++jj)
        C[(size_t)(mbase + jj) * N + n] = acc[mi][ni][jj] + bv;
    }
  }
}

// ---------------------------------------------------------------------------
// Causal flash attention (QBLK=64, heavy-first, double-buffered, setprio).
// XCD-bh swizzle: XCD x owns bh in {4x..4x+3} (K+V = 4MB, L2-resident).
// ---------------------------------------------------------------------------
__global__ __launch_bounds__(256)
void attn_kernel(const __hip_bfloat16* __restrict__ qb,
                 const __hip_bfloat16* __restrict__ kb,
                 const __hip_bfloat16* __restrict__ vtb,
                 __hip_bfloat16* __restrict__ ctx)
{
  __shared__ __hip_bfloat16 Ks[2][64 * 128];
  __shared__ __hip_bfloat16 Vts[2][128 * 64];
  __shared__ __hip_bfloat16 Ps[4][16 * 64];

  const int tid = threadIdx.x, lane = tid & 63, wave = tid >> 6;
  const int fr = lane & 15, fq = lane >> 4;
  const int blk = blockIdx.x;
  const int qi = 31 - (blk >> 5);                      // heavy-first
  const int bh = (blk & 7) * 4 + ((blk >> 3) & 3);     // XCD owns 4 bh
  const int q0 = qi * 64;

  bf16x8 qf[4];
  const int qrow = q0 + wave * 16 + fr;
#pragma unroll
  for (int kf = 0; kf < 4; ++kf)
    qf[kf] = as_bf(*(const short8*)&qb[((size_t)bh * 2048 + qrow) * 128 + kf * 32 + fq * 8]);

  f32x4 acco[8] = {};
  float m_run[4] = {-1e30f, -1e30f, -1e30f, -1e30f};
  float l_run[4] = {0.f, 0.f, 0.f, 0.f};

  char* Pb = (char*)&Ps[wave][0];
  const int nt = qi + 1;

  auto STAGE = [&](int t, int buf) {
    const int k0t = t * 64;
#pragma unroll
    for (int i = 0; i < 4; ++i) {
      int c = wave * 4 + i;
      int kv = c * 4 + fq;
      int cb = (fr * 16) ^ ((kv & 7) << 4);
      gload16(&kb[((size_t)bh * 2048 + k0t + kv) * 128 + (cb >> 1)], &Ks[buf][c * 512]);
    }
#pragma unroll
    for (int i = 0; i < 4; ++i) {
      int c = wave * 4 + i;
      int d = c * 8 + (lane >> 3);
      int cb = ((lane & 7) * 16) ^ ((d & 7) << 4);
      gload16(&vtb[((size_t)bh * 128 + d) * 2048 + k0t + (cb >> 1)], &Vts[buf][c * 512]);
    }
  };

  STAGE(0, 0);
  __syncthreads();

  int cur = 0;
  for (int t = 0; t < nt; ++t) {
    if (t + 1 < nt) STAGE(t + 1, cur ^ 1);
    const char* Kb = (const char*)&Ks[cur][0];
    const char* Vb = (const char*)&Vts[cur][0];
    const int k0 = t * 64;

    f32x4 sacc[4] = {};
    __builtin_amdgcn_s_setprio(1);
#pragma unroll
    for (int kf = 0; kf < 4; ++kf) {
#pragma unroll
      for (int ni = 0; ni < 4; ++ni) {
        int kv = ni * 16 + fr;
        int cb = (kf * 64 + fq * 16) ^ ((kv & 7) << 4);
        bf16x8 kfr = as_bf(*(const short8*)(Kb + kv * 256 + cb));
        sacc[ni] = mfma16(qf[kf], kfr, sacc[ni]);
      }
    }
    __builtin_amdgcn_s_setprio(0);

    const float scale = 0.088388347648318447f;
    float sv[4][4];
    float rmax[4] = {-1e30f, -1e30f, -1e30f, -1e30f};
#pragma unroll
    for (int ni = 0; ni < 4; ++ni) {
      int kv_g = k0 + ni * 16 + fr;
#pragma unroll
      for (int j = 0; j < 4; ++j) {
        int q_g = q0 + wave * 16 + fq * 4 + j;
        float s = sacc[ni][j] * scale;
        if (kv_g > q_g) s = -10000.f;
        sv[ni][j] = s;
        rmax[j] = fmaxf(rmax[j], s);
      }
    }
#pragma unroll
    for (int off = 1; off < 16; off <<= 1)
#pragma unroll
      for (int j = 0; j < 4; ++j)
        rmax[j] = fmaxf(rmax[j], __shfl_xor(rmax[j], off));

    float alpha[4], rsum[4];
#pragma unroll
    for (int j = 0; j < 4; ++j) {
      float mn = fmaxf(m_run[j], rmax[j]);
      alpha[j] = __expf(m_run[j] - mn);
      m_run[j] = mn;
      rsum[j] = 0.f;
    }
#pragma unroll
    for (int ni = 0; ni < 4; ++ni) {
#pragma unroll
      for (int j = 0; j < 4; ++j) {
        float p = __expf(sv[ni][j] - m_run[j]);
        rsum[j] += p;
        int prow = fq * 4 + j;
        int cbw = ((ni * 16 + fr) * 2) ^ ((prow & 7) << 4);
        *(__hip_bfloat16*)(Pb + prow * 128 + cbw) = f2bf(p);
      }
    }
#pragma unroll
    for (int off = 1; off < 16; off <<= 1)
#pragma unroll
      for (int j = 0; j < 4; ++j)
        rsum[j] += __shfl_xor(rsum[j], off);
#pragma unroll
    for (int j = 0; j < 4; ++j)
      l_run[j] = l_run[j] * alpha[j] + rsum[j];

#pragma unroll
    for (int nd = 0; nd < 8; ++nd)
#pragma unroll
      for (int j = 0; j < 4; ++j)
        acco[nd][j] *= alpha[j];

    asm volatile("s_waitcnt lgkmcnt(0)" ::: "memory");
    __builtin_amdgcn_sched_barrier(0);

    __builtin_amdgcn_s_setprio(1);
#pragma unroll
    for (int kf2 = 0; kf2 < 2; ++kf2) {
      int cbp = (kf2 * 64 + fq * 16) ^ ((fr & 7) << 4);
      bf16x8 pa = as_bf(*(const short8*)(Pb + fr * 128 + cbp));
#pragma unroll
      for (int nd = 0; nd < 8; ++nd) {
        int d = nd * 16 + fr;
        int cbv = (kf2 * 64 + fq * 16) ^ ((d & 7) << 4);
        bf16x8 vfr = as_bf(*(const short8*)(Vb + d * 128 + cbv));
        acco[nd] = mfma16(pa, vfr, acco[nd]);
      }
    }
    __builtin_amdgcn_s_setprio(0);
    __syncthreads();
    cur ^= 1;
  }

  const int b = bh >> 4, h = bh & 15;
#pragma unroll
  for (int j = 0; j < 4; ++j) {
    float inv = 1.f / l_run[j];
    int s = q0 + wave * 16 + fq * 4 + j;
#pragma unroll
    for (int nd = 0; nd < 8; ++nd) {
      int d = nd * 16 + fr;
      ctx[(((size_t)b * 2048 + s) * 16 + h) * 128 + d] = f2bf(acco[nd][j] * inv);
    }
  }
}

// ---------------------------------------------------------------------------
extern "C" void kernel_launch(void* const* d_in, const int* in_sizes, int n_in,
                              void* d_out, int out_size, void* d_ws, size_t ws_size,
                              hipStream_t stream)
{
  (void)in_sizes; (void)n_in; (void)out_size; (void)ws_size;
  const float* x       = (const float*)d_in[0];
  const float* w_qkv   = (const float*)d_in[1];
  const float* b_qkv   = (const float*)d_in[2];
  const float* w_dense = (const float*)d_in[3];
  const float* b_dense = (const float*)d_in[4];
  float* out = (float*)d_out;

  char* ws = (char*)d_ws;
  __hip_bfloat16* x_bf     = (__hip_bfloat16*)(ws);                  // 16MB
  __hip_bfloat16* wqkv_t   = (__hip_bfloat16*)(ws + 16777216);       // 24MB
  __hip_bfloat16* wdense_t = (__hip_bfloat16*)(ws + 41943040);       // 8MB
  __hip_bfloat16* qb       = (__hip_bfloat16*)(ws + 50331648);       // 16MB
  __hip_bfloat16* kb       = (__hip_bfloat16*)(ws + 67108864);       // 16MB
  __hip_bfloat16* vtb      = (__hip_bfloat16*)(ws + 83886080);       // 16MB
  __hip_bfloat16* ctx      = (__hip_bfloat16*)(ws + 100663296);      // 16MB

  prep_kernel<<<8192, 256, 0, stream>>>(x, x_bf, w_qkv, wqkv_t, w_dense, wdense_t);
  gemm192_qkv<<<1024, 256, 0, stream>>>(x_bf, wqkv_t, b_qkv,
                                        qb, kb, vtb, 4096, 6144, 2048);
  attn_kernel<<<1024, 256, 0, stream>>>(qb, kb, vtb, ctx);
  // dense: grid (4096/128)*(2048/128) = 32*16 = 512 = 2 exact rounds @2/CU
  gemm128_dense<<<512, 256, 0, stream>>>(ctx, wdense_t, b_dense, out,
                                         4096, 2048, 2048);
}